// Round 5
// baseline (3975.922 us; speedup 1.0000x reference)
//
#include <hip/hip_runtime.h>
#include <hip/hip_bf16.h>
#include <math.h>

// ---------------------------------------------------------------------------
// Model dims: B=2, Cn=3, HI=WI=224, S=196, P=256, D=384, H_TOK=4
// DEPTH=12, H_VIT=6 (dh=64), HID=1536, NCLS=1000
// ---------------------------------------------------------------------------

typedef __attribute__((ext_vector_type(8))) short short8b;
typedef __attribute__((ext_vector_type(4))) float f32x4;

static __device__ __forceinline__ float gelu_exact(float v) {
    return 0.5f * v * (1.0f + erff(v * 0.70710678118654752440f));
}
static __device__ __forceinline__ short bf16s(float f) {
    __hip_bfloat16 h = __float2bfloat16(f);
    return *reinterpret_cast<short*>(&h);
}

// ---------------------------------------------------------------------------
// f32 -> bf16 conversion (n % 4 == 0)
// ---------------------------------------------------------------------------
__global__ __launch_bounds__(256) void cvt_bf16_k(
    const float* __restrict__ src, __hip_bfloat16* __restrict__ dst, int n)
{
    int i = (blockIdx.x * 256 + threadIdx.x) * 4;
    if (i >= n) return;
    float4 v = *reinterpret_cast<const float4*>(src + i);
    dst[i+0] = __float2bfloat16(v.x);
    dst[i+1] = __float2bfloat16(v.y);
    dst[i+2] = __float2bfloat16(v.z);
    dst[i+3] = __float2bfloat16(v.w);
}

// ---------------------------------------------------------------------------
// zero vT key-pad region + barrier counter init
// ---------------------------------------------------------------------------
__global__ __launch_bounds__(256) void init_k(__hip_bfloat16* __restrict__ vT,
                                              int* __restrict__ bar)
{
    int i = blockIdx.x * 256 + threadIdx.x;
    if (i < 64) bar[i] = 0;
    if (i >= 12*64*27) return;
    int c = i % 27, r = i / 27;
    vT[(long)r*224 + 197 + c] = __float2bfloat16(0.f);
}

// ---------------------------------------------------------------------------
// prep: W2[1152][3] = ap_in_w @ fp_w ; b2[1152] = ap_in_b + ap_in_w @ fp_b
// ---------------------------------------------------------------------------
__global__ __launch_bounds__(256) void prep_w2_k(
    const float* __restrict__ ap_in_w, const float* __restrict__ ap_in_b,
    const float* __restrict__ fp_w, const float* __restrict__ fp_b,
    float* __restrict__ W2, float* __restrict__ b2)
{
    int o = blockIdx.x * 256 + threadIdx.x;
    if (o >= 1152) return;
    const float* ar = ap_in_w + (long)o * 384;
    float a0 = 0.f, a1 = 0.f, a2 = 0.f, ab = ap_in_b[o];
    for (int d = 0; d < 384; ++d) {
        float aw = ar[d];
        a0 = fmaf(aw, fp_w[d*3+0], a0);
        a1 = fmaf(aw, fp_w[d*3+1], a1);
        a2 = fmaf(aw, fp_w[d*3+2], a2);
        ab = fmaf(aw, fp_b[d], ab);
    }
    W2[o*3+0] = a0; W2[o*3+1] = a1; W2[o*3+2] = a2; b2[o] = ab;
}

// ---------------------------------------------------------------------------
// prep per-head bilinear form (scaled by 1/sqrt(96))
// ---------------------------------------------------------------------------
__global__ __launch_bounds__(64) void prep_head_k(
    const float* __restrict__ W2, const float* __restrict__ b2,
    float* __restrict__ hGm)
{
    int h = blockIdx.x;
    int lane = threadIdx.x;
    float G00=0,G01=0,G02=0,G10=0,G11=0,G12=0,G20=0,G21=0,G22=0;
    float u0=0,u1=0,u2=0,w0=0,w1=0,w2=0,c0=0;
    for (int d = lane; d < 96; d += 64) {
        int oq = h*96 + d, ok = 384 + h*96 + d;
        float q0=W2[oq*3],q1=W2[oq*3+1],q2=W2[oq*3+2];
        float k0=W2[ok*3],k1=W2[ok*3+1],k2=W2[ok*3+2];
        float bq=b2[oq], bk=b2[ok];
        G00=fmaf(q0,k0,G00); G01=fmaf(q0,k1,G01); G02=fmaf(q0,k2,G02);
        G10=fmaf(q1,k0,G10); G11=fmaf(q1,k1,G11); G12=fmaf(q1,k2,G12);
        G20=fmaf(q2,k0,G20); G21=fmaf(q2,k1,G21); G22=fmaf(q2,k2,G22);
        u0=fmaf(q0,bk,u0); u1=fmaf(q1,bk,u1); u2=fmaf(q2,bk,u2);
        w0=fmaf(k0,bq,w0); w1=fmaf(k1,bq,w1); w2=fmaf(k2,bq,w2);
        c0=fmaf(bq,bk,c0);
    }
    float vals[16] = {G00,G01,G02,u0, G10,G11,G12,u1, G20,G21,G22,u2, w0,w1,w2,c0};
    const float sc = 0.10206207261596577f; // 1/sqrt(96)
    #pragma unroll
    for (int q = 0; q < 16; ++q) {
        float v = vals[q];
        for (int off = 32; off; off >>= 1) v += __shfl_down(v, off);
        if (lane == 0) hGm[h*16 + q] = v * sc;
    }
}

// ---------------------------------------------------------------------------
// Tokenizer attention, 2-pass (no row-max: scores ~1e-3, exp safe; 1/l folded
// into exp arg via pxm.w = -ln(l)). One block per (segment, head, batch).
// ---------------------------------------------------------------------------
__global__ __launch_bounds__(256) void tok_attn_k(
    const float* __restrict__ img, const float* __restrict__ hGm,
    const float* __restrict__ W2, const float* __restrict__ b2,
    __hip_bfloat16* __restrict__ pooledb)
{
    int s = blockIdx.x, h = blockIdx.y, b = blockIdx.z;
    int t = threadIdx.x;
    __shared__ float4 pxm[256];
    __shared__ float4 ylds[256];
    __shared__ float  Ash[256];
    __shared__ float  tsum[3];

    int gy = s / 14, gx = s - gy*14;
    int row = gy*16 + (t >> 4), col = gx*16 + (t & 15);
    long base = ((long)b*3*224 + row)*224 + col;
    float p0 = img[base];
    float p1 = img[base + 224*224];
    float p2 = img[base + 2*224*224];

    const float4* M4 = reinterpret_cast<const float4*>(hGm) + h*4;
    float4 r0 = M4[0], r1 = M4[1], r2 = M4[2], r3 = M4[3];
    float y0 = fmaf(p0,r0.x, fmaf(p1,r0.y, fmaf(p2,r0.z, r0.w)));
    float y1 = fmaf(p0,r1.x, fmaf(p1,r1.y, fmaf(p2,r1.z, r1.w)));
    float y2 = fmaf(p0,r2.x, fmaf(p1,r2.y, fmaf(p2,r2.z, r2.w)));
    float y3 = fmaf(p0,r3.x, fmaf(p1,r3.y, fmaf(p2,r3.z, r3.w)));
    ylds[t] = make_float4(y0,y1,y2,y3);
    pxm[t]  = make_float4(p0,p1,p2,0.f);
    __syncthreads();

    // pass A: l_i = sum_j exp(s_ij)
    float li = 0.f;
    #pragma unroll 4
    for (int j = 0; j < 256; ++j) {
        float4 Y = ylds[j];
        float scr = fmaf(p0,Y.x, fmaf(p1,Y.y, fmaf(p2,Y.z, Y.w)));
        li += __expf(scr);
    }
    pxm[t].w = -__logf(li);
    __syncthreads();

    // pass B: A_j = sum_i exp(s_ij - ln l_i)
    float Aj = 0.f;
    #pragma unroll 4
    for (int i = 0; i < 256; ++i) {
        float4 q = pxm[i];
        float scr = fmaf(q.x,y0, fmaf(q.y,y1, fmaf(q.z,y2, y3))) + q.w;
        Aj += __expf(scr);
    }
    Ash[t] = Aj;
    __syncthreads();

    int w = t >> 6, lane = t & 63;
    if (w < 3) {
        float prt = 0.f;
        for (int j = lane; j < 256; j += 64) {
            const float* pj = reinterpret_cast<const float*>(&pxm[j]);
            prt = fmaf(Ash[j], pj[w], prt);
        }
        for (int off = 32; off; off >>= 1) prt += __shfl_down(prt, off);
        if (lane == 0) tsum[w] = prt;
    }
    __syncthreads();

    if (t < 96) {
        int o = 768 + h*96 + t;
        float v = (W2[o*3]*tsum[0] + W2[o*3+1]*tsum[1] + W2[o*3+2]*tsum[2]) * (1.f/256.f)
                  + b2[o];
        pooledb[((long)(b*196 + s))*384 + h*96 + t] = __float2bfloat16(v);
    }
}

// ---------------------------------------------------------------------------
// MFMA bf16 GEMM, 1 wave per block, 16x64 tile (tokenizer out-proj only).
// ---------------------------------------------------------------------------
__global__ __launch_bounds__(64) void gemm_mfma_k(
    const __hip_bfloat16* __restrict__ A, const __hip_bfloat16* __restrict__ W,
    const float* __restrict__ bias, float* __restrict__ C,
    int M, int N, int K, int lda, int ldw, int ldc)
{
    int l = threadIdx.x;
    int m0 = blockIdx.x * 16, n0 = blockIdx.y * 64;
    int arow = m0 + (l & 15); if (arow >= M) arow = M - 1;
    const __hip_bfloat16* Ap = A + (long)arow * lda + ((l >> 4) << 3);
    const __hip_bfloat16* W0 = W + (long)(n0 + (l & 15)) * ldw + ((l >> 4) << 3);
    long wst = (long)ldw * 16;

    f32x4 acc[4];
    #pragma unroll
    for (int f = 0; f < 4; ++f) acc[f] = f32x4{0.f,0.f,0.f,0.f};

    int niter = K >> 5;
    #pragma unroll 4
    for (int kt = 0; kt < niter; ++kt) {
        int k = kt << 5;
        short8b a  = *reinterpret_cast<const short8b*>(Ap + k);
        short8b b0 = *reinterpret_cast<const short8b*>(W0 + k);
        short8b b1 = *reinterpret_cast<const short8b*>(W0 + wst + k);
        short8b b2 = *reinterpret_cast<const short8b*>(W0 + 2*wst + k);
        short8b b3 = *reinterpret_cast<const short8b*>(W0 + 3*wst + k);
        acc[0] = __builtin_amdgcn_mfma_f32_16x16x32_bf16(a, b0, acc[0], 0, 0, 0);
        acc[1] = __builtin_amdgcn_mfma_f32_16x16x32_bf16(a, b1, acc[1], 0, 0, 0);
        acc[2] = __builtin_amdgcn_mfma_f32_16x16x32_bf16(a, b2, acc[2], 0, 0, 0);
        acc[3] = __builtin_amdgcn_mfma_f32_16x16x32_bf16(a, b3, acc[3], 0, 0, 0);
    }

    int cl = l & 15;
    int rbase = m0 + ((l >> 4) << 2);
    #pragma unroll
    for (int f = 0; f < 4; ++f) {
        int n = n0 + f*16 + cl;
        float bv = bias ? bias[n] : 0.f;
        #pragma unroll
        for (int r = 0; r < 4; ++r) {
            int m = rbase + r;
            if (m >= M) continue;
            C[(long)m*ldc + n] = acc[f][r] + bv;
        }
    }
}

// ---------------------------------------------------------------------------
// x0 = concat(cls, tok) + pos_embed
// ---------------------------------------------------------------------------
__global__ __launch_bounds__(256) void build_x0_k(
    const float* __restrict__ tok, const float* __restrict__ cls,
    const float* __restrict__ pos, float* __restrict__ x)
{
    int idx = blockIdx.x*256 + threadIdx.x;
    if (idx >= 2*197*384) return;
    int d = idx % 384;
    int n = (idx / 384) % 197;
    int b = idx / (384*197);
    float v = (n == 0) ? cls[d] : tok[((long)b*196 + (n-1))*384 + d];
    x[idx] = v + pos[n*384 + d];
}

// ---------------------------------------------------------------------------
// Global barrier: monotonic arrival counter, device-scope. 256 blocks.
// ---------------------------------------------------------------------------
static __device__ __forceinline__ void gbar(int* bar, int target)
{
    __syncthreads();
    if (threadIdx.x == 0) {
        __threadfence();                    // release my writes (agent scope)
        atomicAdd(bar, 1);                  // device-scope by default
        while (__hip_atomic_load(bar, __ATOMIC_ACQUIRE,
                                 __HIP_MEMORY_SCOPE_AGENT) < target)
            __builtin_amdgcn_s_sleep(2);
        __threadfence();                    // acquire others' writes
    }
    __syncthreads();
}

// ---------------------------------------------------------------------------
// MEGA persistent kernel: entire ViT trunk (12 layers) + final LN + head.
// Normal launch, 256 blocks x 256 threads (1 block/CU co-resident).
// ---------------------------------------------------------------------------
struct MegaArgs {
    float* x;
    const float *ln1_g, *ln1_b, *ln2_g, *ln2_b;
    const float *qkv_b, *proj_b, *fc1_b, *fc2_b;
    const __hip_bfloat16 *qkvwb, *projwb, *fc1wb, *fc2wb;
    __hip_bfloat16 *qb, *kb, *vT, *attnb, *hbufb;
    const float *norm_g, *norm_b, *head_w, *head_b;
    float* xnf;
    float* out;
    int* bar;
};

__global__ __launch_bounds__(256, 1) void mega_k(MegaArgs A)
{
    __shared__ __align__(16) short lp[4][16*232];
    int tid = threadIdx.x;
    int wid = tid >> 6, l = tid & 63;
    int gw = wid * 256 + blockIdx.x;        // interleaved global wave id, 0..1023
    int cl = l & 15, hi = l >> 4;
    int rnd = 0;

    for (int layer = 0; layer < 12; ++layer) {
        const __hip_bfloat16* qkvw = A.qkvwb + (long)layer*1152*384;
        const __hip_bfloat16* projw = A.projwb + (long)layer*384*384;
        const __hip_bfloat16* fc1w = A.fc1wb + (long)layer*1536*384;
        const __hip_bfloat16* fc2w = A.fc2wb + (long)layer*384*1536;

        // ---- S1: LN1 + QKV, scatter to qb/kb (q x0.125) / vT ----
        if (gw < 450) {
            int mt = gw % 25, nt = gw / 25;
            int m0 = mt*16, n0 = nt*64;
            int row = m0 + cl; if (row >= 394) row = 393;
            const float* xp = A.x + (long)row*384 + (hi << 3);
            float sum = 0.f, sq = 0.f;
            #pragma unroll
            for (int t = 0; t < 12; ++t) {
                float4 v0 = *reinterpret_cast<const float4*>(xp + t*32);
                float4 v1 = *reinterpret_cast<const float4*>(xp + t*32 + 4);
                sum += v0.x+v0.y+v0.z+v0.w + v1.x+v1.y+v1.z+v1.w;
                sq  += v0.x*v0.x+v0.y*v0.y+v0.z*v0.z+v0.w*v0.w
                     + v1.x*v1.x+v1.y*v1.y+v1.z*v1.z+v1.w*v1.w;
            }
            sum += __shfl_xor(sum, 16); sum += __shfl_xor(sum, 32);
            sq  += __shfl_xor(sq, 16);  sq  += __shfl_xor(sq, 32);
            float mean = sum * (1.f/384.f);
            float var  = sq * (1.f/384.f) - mean*mean;
            float rstd = rsqrtf(var + 1e-6f);
            const float* g = A.ln1_g + layer*384;
            const float* b = A.ln1_b + layer*384;
            const __hip_bfloat16* Wp = qkvw + (long)(n0 + cl)*384 + (hi << 3);
            f32x4 acc[4];
            #pragma unroll
            for (int f = 0; f < 4; ++f) acc[f] = f32x4{0.f,0.f,0.f,0.f};
            #pragma unroll 2
            for (int t = 0; t < 12; ++t) {
                int k = t*32 + (hi << 3);
                float4 v0 = *reinterpret_cast<const float4*>(xp + t*32);
                float4 v1 = *reinterpret_cast<const float4*>(xp + t*32 + 4);
                float4 g0 = *reinterpret_cast<const float4*>(g + k);
                float4 g1 = *reinterpret_cast<const float4*>(g + k + 4);
                float4 bb0 = *reinterpret_cast<const float4*>(b + k);
                float4 bb1 = *reinterpret_cast<const float4*>(b + k + 4);
                short8b a;
                a[0] = bf16s(fmaf((v0.x-mean)*rstd, g0.x, bb0.x));
                a[1] = bf16s(fmaf((v0.y-mean)*rstd, g0.y, bb0.y));
                a[2] = bf16s(fmaf((v0.z-mean)*rstd, g0.z, bb0.z));
                a[3] = bf16s(fmaf((v0.w-mean)*rstd, g0.w, bb0.w));
                a[4] = bf16s(fmaf((v1.x-mean)*rstd, g1.x, bb1.x));
                a[5] = bf16s(fmaf((v1.y-mean)*rstd, g1.y, bb1.y));
                a[6] = bf16s(fmaf((v1.z-mean)*rstd, g1.z, bb1.z));
                a[7] = bf16s(fmaf((v1.w-mean)*rstd, g1.w, bb1.w));
                short8b w0 = *reinterpret_cast<const short8b*>(Wp + t*32);
                short8b w1 = *reinterpret_cast<const short8b*>(Wp + 16L*384 + t*32);
                short8b w2 = *reinterpret_cast<const short8b*>(Wp + 32L*384 + t*32);
                short8b w3 = *reinterpret_cast<const short8b*>(Wp + 48L*384 + t*32);
                acc[0] = __builtin_amdgcn_mfma_f32_16x16x32_bf16(a, w0, acc[0], 0, 0, 0);
                acc[1] = __builtin_amdgcn_mfma_f32_16x16x32_bf16(a, w1, acc[1], 0, 0, 0);
                acc[2] = __builtin_amdgcn_mfma_f32_16x16x32_bf16(a, w2, acc[2], 0, 0, 0);
                acc[3] = __builtin_amdgcn_mfma_f32_16x16x32_bf16(a, w3, acc[3], 0, 0, 0);
            }
            int rb = hi << 2;
            #pragma unroll
            for (int f = 0; f < 4; ++f) {
                int n = n0 + f*16 + cl;
                float bv = A.qkv_b[layer*1152 + n];
                #pragma unroll
                for (int r = 0; r < 4; ++r) {
                    int m = m0 + rb + r;
                    if (m >= 394) continue;
                    float v = acc[f][r] + bv;
                    int bb = (m >= 197) ? 1 : 0;
                    int tokr = m - bb*197;
                    if (n < 384) {
                        int h = n >> 6, ch = n & 63;
                        A.qb[((long)(bb*6 + h)*208 + tokr)*64 + ch] = __float2bfloat16(v * 0.125f);
                    } else if (n < 768) {
                        int nn = n - 384, h = nn >> 6, ch = nn & 63;
                        A.kb[((long)(bb*6 + h)*208 + tokr)*64 + ch] = __float2bfloat16(v);
                    } else {
                        int nn = n - 768, h = nn >> 6, ch = nn & 63;
                        A.vT[((long)(bb*6 + h)*64 + ch)*224 + tokr] = __float2bfloat16(v);
                    }
                }
            }
        }
        gbar(A.bar, (++rnd) * 256);

        // ---- S2: flash attention ----
        {
            bool act = gw < 156;
            short* lps = lp[wid];
            int qt = gw % 13, bh = gw / 13;
            if (act) {
                int q0 = qt * 16;
                if (l < 32) {
                    int prow = l >> 1, hf = l & 1;
                    *reinterpret_cast<int4*>(lps + prow*232 + 208 + hf*8) = int4{0,0,0,0};
                }
                const __hip_bfloat16* Qp = A.qb + ((long)bh*208 + q0 + cl)*64 + (hi << 3);
                const __hip_bfloat16* Kp = A.kb + ((long)bh*208 + cl)*64 + (hi << 3);
                f32x4 s[13];
                #pragma unroll
                for (int f = 0; f < 13; ++f) s[f] = f32x4{0.f,0.f,0.f,0.f};
                #pragma unroll
                for (int kt = 0; kt < 2; ++kt) {
                    short8b a = *reinterpret_cast<const short8b*>(Qp + kt*32);
                    #pragma unroll
                    for (int f = 0; f < 13; ++f) {
                        short8b kk = *reinterpret_cast<const short8b*>(Kp + (long)f*16*64 + kt*32);
                        s[f] = __builtin_amdgcn_mfma_f32_16x16x32_bf16(a, kk, s[f], 0, 0, 0);
                    }
                }
                if (cl >= 5) s[12] = f32x4{-1e30f,-1e30f,-1e30f,-1e30f};
                #pragma unroll
                for (int r = 0; r < 4; ++r) {
                    float m = s[0][r];
                    #pragma unroll
                    for (int f = 1; f < 13; ++f) m = fmaxf(m, s[f][r]);
                    m = fmaxf(m, __shfl_xor(m, 1));
                    m = fmaxf(m, __shfl_xor(m, 2));
                    m = fmaxf(m, __shfl_xor(m, 4));
                    m = fmaxf(m, __shfl_xor(m, 8));
                    float e[13]; float ssum = 0.f;
                    #pragma unroll
                    for (int f = 0; f < 13; ++f) { e[f] = __expf(s[f][r] - m); ssum += e[f]; }
                    ssum += __shfl_xor(ssum, 1);
                    ssum += __shfl_xor(ssum, 2);
                    ssum += __shfl_xor(ssum, 4);
                    ssum += __shfl_xor(ssum, 8);
                    float ri = 1.f / ssum;
                    int prow = (hi << 2) + r;
                    #pragma unroll
                    for (int f = 0; f < 13; ++f)
                        lps[prow*232 + f*16 + cl] = bf16s(e[f] * ri);
                }
            }
            __syncthreads();
            if (act) {
                int q0 = qt * 16;
                f32x4 o[4];
                #pragma unroll
                for (int f = 0; f < 4; ++f) o[f] = f32x4{0.f,0.f,0.f,0.f};
                const __hip_bfloat16* Vp = A.vT + ((long)bh*64 + cl)*224 + (hi << 3);
                #pragma unroll
                for (int kt = 0; kt < 7; ++kt) {
                    short8b pa = *reinterpret_cast<const short8b*>(&lps[cl*232 + (hi << 3) + kt*32]);
                    #pragma unroll
                    for (int f2 = 0; f2 < 4; ++f2) {
                        short8b vb = *reinterpret_cast<const short8b*>(Vp + (long)f2*16*224 + kt*32);
                        o[f2] = __builtin_amdgcn_mfma_f32_16x16x32_bf16(pa, vb, o[f2], 0, 0, 0);
                    }
                }
                int b = bh / 6, h = bh - b*6;
                #pragma unroll
                for (int f2 = 0; f2 < 4; ++f2) {
                    int ch = h*64 + f2*16 + cl;
                    #pragma unroll
                    for (int r = 0; r < 4; ++r) {
                        int qr = q0 + (hi << 2) + r;
                        if (qr < 197)
                            A.attnb[((long)(b*197 + qr))*384 + ch] = __float2bfloat16(o[f2][r]);
                    }
                }
            }
        }
        gbar(A.bar, (++rnd) * 256);

        // ---- S3: x += attn @ proj_w^T + proj_b ----
        if (gw < 150) {
            int mt = gw % 25, nt = gw / 25;
            int m0 = mt*16, n0 = nt*64;
            int arow = m0 + cl; if (arow >= 394) arow = 393;
            const __hip_bfloat16* Ap = A.attnb + (long)arow*384 + (hi << 3);
            const __hip_bfloat16* W0 = projw + (long)(n0 + cl)*384 + (hi << 3);
            f32x4 acc[4];
            #pragma unroll
            for (int f = 0; f < 4; ++f) acc[f] = f32x4{0.f,0.f,0.f,0.f};
            #pragma unroll 4
            for (int kt = 0; kt < 12; ++kt) {
                int k = kt << 5;
                short8b a  = *reinterpret_cast<const short8b*>(Ap + k);
                short8b b0 = *reinterpret_cast<const short8b*>(W0 + k);
                short8b b1 = *reinterpret_cast<const short8b*>(W0 + 16L*384 + k);
                short8b b2 = *reinterpret_cast<const short8b*>(W0 + 32L*384 + k);
                short8b b3 = *reinterpret_cast<const short8b*>(W0 + 48L*384 + k);
                acc[0] = __builtin_amdgcn_mfma_f32_16x16x32_bf16(a, b0, acc[0], 0, 0, 0);
                acc[1] = __builtin_amdgcn_mfma_f32_16x16x32_bf16(a, b1, acc[1], 0, 0, 0);
                acc[2] = __builtin_amdgcn_mfma_f32_16x16x32_bf16(a, b2, acc[2], 0, 0, 0);
                acc[3] = __builtin_amdgcn_mfma_f32_16x16x32_bf16(a, b3, acc[3], 0, 0, 0);
            }
            int rb = hi << 2;
            #pragma unroll
            for (int f = 0; f < 4; ++f) {
                int n = n0 + f*16 + cl;
                float bv = A.proj_b[layer*384 + n];
                #pragma unroll
                for (int r = 0; r < 4; ++r) {
                    int m = m0 + rb + r;
                    if (m >= 394) continue;
                    A.x[(long)m*384 + n] += acc[f][r] + bv;
                }
            }
        }
        gbar(A.bar, (++rnd) * 256);

        // ---- S4: LN2 + FC1 + gelu -> hbufb ----
        if (gw < 600) {
            int mt = gw % 25, nt = gw / 25;
            int m0 = mt*16, n0 = nt*64;
            int row = m0 + cl; if (row >= 394) row = 393;
            const float* xp = A.x + (long)row*384 + (hi << 3);
            float sum = 0.f, sq = 0.f;
            #pragma unroll
            for (int t = 0; t < 12; ++t) {
                float4 v0 = *reinterpret_cast<const float4*>(xp + t*32);
                float4 v1 = *reinterpret_cast<const float4*>(xp + t*32 + 4);
                sum += v0.x+v0.y+v0.z+v0.w + v1.x+v1.y+v1.z+v1.w;
                sq  += v0.x*v0.x+v0.y*v0.y+v0.z*v0.z+v0.w*v0.w
                     + v1.x*v1.x+v1.y*v1.y+v1.z*v1.z+v1.w*v1.w;
            }
            sum += __shfl_xor(sum, 16); sum += __shfl_xor(sum, 32);
            sq  += __shfl_xor(sq, 16);  sq  += __shfl_xor(sq, 32);
            float mean = sum * (1.f/384.f);
            float var  = sq * (1.f/384.f) - mean*mean;
            float rstd = rsqrtf(var + 1e-6f);
            const float* g = A.ln2_g + layer*384;
            const float* b = A.ln2_b + layer*384;
            const __hip_bfloat16* Wp = fc1w + (long)(n0 + cl)*384 + (hi << 3);
            f32x4 acc[4];
            #pragma unroll
            for (int f = 0; f < 4; ++f) acc[f] = f32x4{0.f,0.f,0.f,0.f};
            #pragma unroll 2
            for (int t = 0; t < 12; ++t) {
                int k = t*32 + (hi << 3);
                float4 v0 = *reinterpret_cast<const float4*>(xp + t*32);
                float4 v1 = *reinterpret_cast<const float4*>(xp + t*32 + 4);
                float4 g0 = *reinterpret_cast<const float4*>(g + k);
                float4 g1 = *reinterpret_cast<const float4*>(g + k + 4);
                float4 bb0 = *reinterpret_cast<const float4*>(b + k);
                float4 bb1 = *reinterpret_cast<const float4*>(b + k + 4);
                short8b a;
                a[0] = bf16s(fmaf((v0.x-mean)*rstd, g0.x, bb0.x));
                a[1] = bf16s(fmaf((v0.y-mean)*rstd, g0.y, bb0.y));
                a[2] = bf16s(fmaf((v0.z-mean)*rstd, g0.z, bb0.z));
                a[3] = bf16s(fmaf((v0.w-mean)*rstd, g0.w, bb0.w));
                a[4] = bf16s(fmaf((v1.x-mean)*rstd, g1.x, bb1.x));
                a[5] = bf16s(fmaf((v1.y-mean)*rstd, g1.y, bb1.y));
                a[6] = bf16s(fmaf((v1.z-mean)*rstd, g1.z, bb1.z));
                a[7] = bf16s(fmaf((v1.w-mean)*rstd, g1.w, bb1.w));
                short8b w0 = *reinterpret_cast<const short8b*>(Wp + t*32);
                short8b w1 = *reinterpret_cast<const short8b*>(Wp + 16L*384 + t*32);
                short8b w2 = *reinterpret_cast<const short8b*>(Wp + 32L*384 + t*32);
                short8b w3 = *reinterpret_cast<const short8b*>(Wp + 48L*384 + t*32);
                acc[0] = __builtin_amdgcn_mfma_f32_16x16x32_bf16(a, w0, acc[0], 0, 0, 0);
                acc[1] = __builtin_amdgcn_mfma_f32_16x16x32_bf16(a, w1, acc[1], 0, 0, 0);
                acc[2] = __builtin_amdgcn_mfma_f32_16x16x32_bf16(a, w2, acc[2], 0, 0, 0);
                acc[3] = __builtin_amdgcn_mfma_f32_16x16x32_bf16(a, w3, acc[3], 0, 0, 0);
            }
            int rb = hi << 2;
            #pragma unroll
            for (int f = 0; f < 4; ++f) {
                int n = n0 + f*16 + cl;
                float bv = A.fc1_b[layer*1536 + n];
                #pragma unroll
                for (int r = 0; r < 4; ++r) {
                    int m = m0 + rb + r;
                    if (m >= 394) continue;
                    A.hbufb[(long)m*1536 + n] = __float2bfloat16(gelu_exact(acc[f][r] + bv));
                }
            }
        }
        gbar(A.bar, (++rnd) * 256);

        // ---- S5: x += hbuf @ fc2_w^T + fc2_b ----
        if (gw < 150) {
            int mt = gw % 25, nt = gw / 25;
            int m0 = mt*16, n0 = nt*64;
            int arow = m0 + cl; if (arow >= 394) arow = 393;
            const __hip_bfloat16* Ap = A.hbufb + (long)arow*1536 + (hi << 3);
            const __hip_bfloat16* W0 = fc2w + (long)(n0 + cl)*1536 + (hi << 3);
            f32x4 acc[4];
            #pragma unroll
            for (int f = 0; f < 4; ++f) acc[f] = f32x4{0.f,0.f,0.f,0.f};
            #pragma unroll 4
            for (int kt = 0; kt < 48; ++kt) {
                int k = kt << 5;
                short8b a  = *reinterpret_cast<const short8b*>(Ap + k);
                short8b b0 = *reinterpret_cast<const short8b*>(W0 + k);
                short8b b1 = *reinterpret_cast<const short8b*>(W0 + 16L*1536 + k);
                short8b b2 = *reinterpret_cast<const short8b*>(W0 + 32L*1536 + k);
                short8b b3 = *reinterpret_cast<const short8b*>(W0 + 48L*1536 + k);
                acc[0] = __builtin_amdgcn_mfma_f32_16x16x32_bf16(a, b0, acc[0], 0, 0, 0);
                acc[1] = __builtin_amdgcn_mfma_f32_16x16x32_bf16(a, b1, acc[1], 0, 0, 0);
                acc[2] = __builtin_amdgcn_mfma_f32_16x16x32_bf16(a, b2, acc[2], 0, 0, 0);
                acc[3] = __builtin_amdgcn_mfma_f32_16x16x32_bf16(a, b3, acc[3], 0, 0, 0);
            }
            int rb = hi << 2;
            #pragma unroll
            for (int f = 0; f < 4; ++f) {
                int n = n0 + f*16 + cl;
                float bv = A.fc2_b[layer*384 + n];
                #pragma unroll
                for (int r = 0; r < 4; ++r) {
                    int m = m0 + rb + r;
                    if (m >= 394) continue;
                    A.x[(long)m*384 + n] += acc[f][r] + bv;
                }
            }
        }
        gbar(A.bar, (++rnd) * 256);
    }

    // ---- S6: final LN -> xnf (f32) ----
    if (gw < 25) {
        int m0 = gw * 16;
        int row = m0 + cl; if (row >= 394) row = 393;
        const float* xp = A.x + (long)row*384 + (hi << 3);
        float sum = 0.f, sq = 0.f;
        #pragma unroll
        for (int t = 0; t < 12; ++t) {
            float4 v0 = *reinterpret_cast<const float4*>(xp + t*32);
            float4 v1 = *reinterpret_cast<const float4*>(xp + t*32 + 4);
            sum += v0.x+v0.y+v0.z+v0.w + v1.x+v1.y+v1.z+v1.w;
            sq  += v0.x*v0.x+v0.y*v0.y+v0.z*v0.z+v0.w*v0.w
                 + v1.x*v1.x+v1.y*v1.y+v1.z*v1.z+v1.w*v1.w;
        }
        sum += __shfl_xor(sum, 16); sum += __shfl_xor(sum, 32);
        sq  += __shfl_xor(sq, 16);  sq  += __shfl_xor(sq, 32);
        float mean = sum * (1.f/384.f);
        float var  = sq * (1.f/384.f) - mean*mean;
        float rstd = rsqrtf(var + 1e-6f);
        if (m0 + cl < 394) {
            float* yp = A.xnf + (long)(m0 + cl)*384 + (hi << 3);
            #pragma unroll
            for (int t = 0; t < 12; ++t) {
                int k = t*32 + (hi << 3);
                float4 v0 = *reinterpret_cast<const float4*>(xp + t*32);
                float4 v1 = *reinterpret_cast<const float4*>(xp + t*32 + 4);
                float4 o0, o1;
                o0.x = fmaf((v0.x-mean)*rstd, A.norm_g[k+0], A.norm_b[k+0]);
                o0.y = fmaf((v0.y-mean)*rstd, A.norm_g[k+1], A.norm_b[k+1]);
                o0.z = fmaf((v0.z-mean)*rstd, A.norm_g[k+2], A.norm_b[k+2]);
                o0.w = fmaf((v0.w-mean)*rstd, A.norm_g[k+3], A.norm_b[k+3]);
                o1.x = fmaf((v1.x-mean)*rstd, A.norm_g[k+4], A.norm_b[k+4]);
                o1.y = fmaf((v1.y-mean)*rstd, A.norm_g[k+5], A.norm_b[k+5]);
                o1.z = fmaf((v1.z-mean)*rstd, A.norm_g[k+6], A.norm_b[k+6]);
                o1.w = fmaf((v1.w-mean)*rstd, A.norm_g[k+7], A.norm_b[k+7]);
                *reinterpret_cast<float4*>(yp + t*32) = o0;
                *reinterpret_cast<float4*>(yp + t*32 + 4) = o1;
            }
        }
    }
    gbar(A.bar, (++rnd) * 256);

    // ---- S7: head out[2][1000] ----
    {
        int idx = gw * 64 + l;
        if (idx < 2000) {
            int m = idx / 1000, n = idx - m*1000;
            const float* xr = A.xnf + (long)(m*197)*384;
            const float* wr = A.head_w + (long)n*384;
            float accv = A.head_b[n];
            for (int d = 0; d < 384; d += 4) {
                float4 xv = *reinterpret_cast<const float4*>(xr + d);
                float4 wv = *reinterpret_cast<const float4*>(wr + d);
                accv = fmaf(xv.x,wv.x, fmaf(xv.y,wv.y, fmaf(xv.z,wv.z, fmaf(xv.w,wv.w, accv))));
            }
            A.out[m*1000 + n] = accv;
        }
    }
}

// ---------------------------------------------------------------------------
extern "C" void kernel_launch(void* const* d_in, const int* in_sizes, int n_in,
                              void* d_out, int out_size, void* d_ws, size_t ws_size,
                              hipStream_t stream)
{
    const float* img      = (const float*)d_in[0];
    const float* fp_w     = (const float*)d_in[2];
    const float* fp_b     = (const float*)d_in[3];
    const float* ap_in_w  = (const float*)d_in[4];
    const float* ap_in_b  = (const float*)d_in[5];
    const float* ap_out_w = (const float*)d_in[6];
    const float* ap_out_b = (const float*)d_in[7];
    const float* cls_tok  = (const float*)d_in[8];
    const float* pos_emb  = (const float*)d_in[9];
    const float* ln1_g    = (const float*)d_in[10];
    const float* ln1_b    = (const float*)d_in[11];
    const float* qkv_w    = (const float*)d_in[12];
    const float* qkv_b    = (const float*)d_in[13];
    const float* proj_w   = (const float*)d_in[14];
    const float* proj_b   = (const float*)d_in[15];
    const float* ln2_g    = (const float*)d_in[16];
    const float* ln2_b    = (const float*)d_in[17];
    const float* fc1_w    = (const float*)d_in[18];
    const float* fc1_b    = (const float*)d_in[19];
    const float* fc2_w    = (const float*)d_in[20];
    const float* fc2_b    = (const float*)d_in[21];
    const float* norm_g   = (const float*)d_in[22];
    const float* norm_b   = (const float*)d_in[23];
    const float* head_w   = (const float*)d_in[24];
    const float* head_b   = (const float*)d_in[25];
    (void)in_sizes; (void)n_in; (void)out_size; (void)ws_size;
    float* out = (float*)d_out;

    float* ws = (float*)d_ws;
    size_t off = 0;
    auto alloc = [&](size_t nfl) { float* p = ws + off; off += (nfl + 63) & ~(size_t)63; return p; };
    float* W2     = alloc(1152*3);
    float* b2     = alloc(1152);
    float* hGm    = alloc(64);
    float* tok    = alloc(392L*384);
    float* x      = alloc(394L*384);
    float* xnf    = alloc(394L*384);
    int*   bar    = (int*)alloc(64);
    __hip_bfloat16* pooledb = (__hip_bfloat16*)alloc(392L*384/2);
    __hip_bfloat16* attnb   = (__hip_bfloat16*)alloc(394L*384/2 + 64);
    __hip_bfloat16* hbufb   = (__hip_bfloat16*)alloc(394L*1536/2 + 64);
    __hip_bfloat16* qb      = (__hip_bfloat16*)alloc(12L*208*64/2);
    __hip_bfloat16* kb      = (__hip_bfloat16*)alloc(12L*208*64/2);
    __hip_bfloat16* vT      = (__hip_bfloat16*)alloc(12L*64*224/2);
    __hip_bfloat16* qkvwb   = (__hip_bfloat16*)alloc(12L*1152*384/2);
    __hip_bfloat16* projwb  = (__hip_bfloat16*)alloc(12L*384*384/2);
    __hip_bfloat16* fc1wb   = (__hip_bfloat16*)alloc(12L*1536*384/2);
    __hip_bfloat16* fc2wb   = (__hip_bfloat16*)alloc(12L*384*1536/2);
    __hip_bfloat16* apoutwb = (__hip_bfloat16*)alloc(384L*384/2);

    // ---- weight conversion + pad/barrier init ----
    {
        int n1 = 12*1152*384, n2 = 12*384*384, n3 = 12*1536*384, n4 = 384*384;
        cvt_bf16_k<<<(n1/4 + 255)/256, 256, 0, stream>>>(qkv_w,  qkvwb,  n1);
        cvt_bf16_k<<<(n2/4 + 255)/256, 256, 0, stream>>>(proj_w, projwb, n2);
        cvt_bf16_k<<<(n3/4 + 255)/256, 256, 0, stream>>>(fc1_w,  fc1wb,  n3);
        cvt_bf16_k<<<(n3/4 + 255)/256, 256, 0, stream>>>(fc2_w,  fc2wb,  n3);
        cvt_bf16_k<<<(n4/4 + 255)/256, 256, 0, stream>>>(ap_out_w, apoutwb, n4);
        init_k<<<(12*64*27 + 255)/256, 256, 0, stream>>>(vT, bar);
    }

    // ---- tokenizer ----
    prep_w2_k<<<5, 256, 0, stream>>>(ap_in_w, ap_in_b, fp_w, fp_b, W2, b2);
    prep_head_k<<<4, 64, 0, stream>>>(W2, b2, hGm);
    tok_attn_k<<<dim3(196,4,2), 256, 0, stream>>>(img, hGm, W2, b2, pooledb);
    gemm_mfma_k<<<dim3(25,6), 64, 0, stream>>>(
        pooledb, apoutwb, ap_out_b, tok, 392, 384, 384, 384, 384, 384);
    build_x0_k<<<(2*197*384 + 255)/256, 256, 0, stream>>>(tok, cls_tok, pos_emb, x);

    // ---- trunk + head: one persistent kernel with global barrier ----
    MegaArgs ma;
    ma.x = x;
    ma.ln1_g = ln1_g; ma.ln1_b = ln1_b; ma.ln2_g = ln2_g; ma.ln2_b = ln2_b;
    ma.qkv_b = qkv_b; ma.proj_b = proj_b; ma.fc1_b = fc1_b; ma.fc2_b = fc2_b;
    ma.qkvwb = qkvwb; ma.projwb = projwb; ma.fc1wb = fc1wb; ma.fc2wb = fc2wb;
    ma.qb = qb; ma.kb = kb; ma.vT = vT; ma.attnb = attnb; ma.hbufb = hbufb;
    ma.norm_g = norm_g; ma.norm_b = norm_b; ma.head_w = head_w; ma.head_b = head_b;
    ma.xnf = xnf; ma.out = out; ma.bar = bar;
    mega_k<<<256, 256, 0, stream>>>(ma);
}

// Round 6
// 1947.492 us; speedup vs baseline: 2.0416x; 2.0416x over previous
//
#include <hip/hip_runtime.h>
#include <hip/hip_bf16.h>
#include <math.h>

// ---------------------------------------------------------------------------
// Model dims: B=2, Cn=3, HI=WI=224, S=196, P=256, D=384, H_TOK=4
// DEPTH=12, H_VIT=6 (dh=64), HID=1536, NCLS=1000
// ---------------------------------------------------------------------------

typedef __attribute__((ext_vector_type(8))) short short8b;
typedef __attribute__((ext_vector_type(4))) float f32x4;

static __device__ __forceinline__ float gelu_exact(float v) {
    return 0.5f * v * (1.0f + erff(v * 0.70710678118654752440f));
}
static __device__ __forceinline__ short bf16s(float f) {
    __hip_bfloat16 h = __float2bfloat16(f);
    return *reinterpret_cast<short*>(&h);
}

// ---------------------------------------------------------------------------
// f32 -> bf16 conversion (n % 4 == 0)
// ---------------------------------------------------------------------------
__global__ __launch_bounds__(256) void cvt_bf16_k(
    const float* __restrict__ src, __hip_bfloat16* __restrict__ dst, int n)
{
    int i = (blockIdx.x * 256 + threadIdx.x) * 4;
    if (i >= n) return;
    float4 v = *reinterpret_cast<const float4*>(src + i);
    dst[i+0] = __float2bfloat16(v.x);
    dst[i+1] = __float2bfloat16(v.y);
    dst[i+2] = __float2bfloat16(v.z);
    dst[i+3] = __float2bfloat16(v.w);
}

// ---------------------------------------------------------------------------
// zero vT key-pad region + barrier state init (1024 ints)
// ---------------------------------------------------------------------------
__global__ __launch_bounds__(256) void init_k(__hip_bfloat16* __restrict__ vT,
                                              int* __restrict__ bar)
{
    int i = blockIdx.x * 256 + threadIdx.x;
    if (i < 1024) bar[i] = 0;
    if (i >= 12*64*27) return;
    int c = i % 27, r = i / 27;
    vT[(long)r*224 + 197 + c] = __float2bfloat16(0.f);
}

// ---------------------------------------------------------------------------
// prep: W2[1152][3] = ap_in_w @ fp_w ; b2[1152] = ap_in_b + ap_in_w @ fp_b
// ---------------------------------------------------------------------------
__global__ __launch_bounds__(256) void prep_w2_k(
    const float* __restrict__ ap_in_w, const float* __restrict__ ap_in_b,
    const float* __restrict__ fp_w, const float* __restrict__ fp_b,
    float* __restrict__ W2, float* __restrict__ b2)
{
    int o = blockIdx.x * 256 + threadIdx.x;
    if (o >= 1152) return;
    const float* ar = ap_in_w + (long)o * 384;
    float a0 = 0.f, a1 = 0.f, a2 = 0.f, ab = ap_in_b[o];
    for (int d = 0; d < 384; ++d) {
        float aw = ar[d];
        a0 = fmaf(aw, fp_w[d*3+0], a0);
        a1 = fmaf(aw, fp_w[d*3+1], a1);
        a2 = fmaf(aw, fp_w[d*3+2], a2);
        ab = fmaf(aw, fp_b[d], ab);
    }
    W2[o*3+0] = a0; W2[o*3+1] = a1; W2[o*3+2] = a2; b2[o] = ab;
}

// ---------------------------------------------------------------------------
// prep per-head bilinear form (scaled by 1/sqrt(96))
// ---------------------------------------------------------------------------
__global__ __launch_bounds__(64) void prep_head_k(
    const float* __restrict__ W2, const float* __restrict__ b2,
    float* __restrict__ hGm)
{
    int h = blockIdx.x;
    int lane = threadIdx.x;
    float G00=0,G01=0,G02=0,G10=0,G11=0,G12=0,G20=0,G21=0,G22=0;
    float u0=0,u1=0,u2=0,w0=0,w1=0,w2=0,c0=0;
    for (int d = lane; d < 96; d += 64) {
        int oq = h*96 + d, ok = 384 + h*96 + d;
        float q0=W2[oq*3],q1=W2[oq*3+1],q2=W2[oq*3+2];
        float k0=W2[ok*3],k1=W2[ok*3+1],k2=W2[ok*3+2];
        float bq=b2[oq], bk=b2[ok];
        G00=fmaf(q0,k0,G00); G01=fmaf(q0,k1,G01); G02=fmaf(q0,k2,G02);
        G10=fmaf(q1,k0,G10); G11=fmaf(q1,k1,G11); G12=fmaf(q1,k2,G12);
        G20=fmaf(q2,k0,G20); G21=fmaf(q2,k1,G21); G22=fmaf(q2,k2,G22);
        u0=fmaf(q0,bk,u0); u1=fmaf(q1,bk,u1); u2=fmaf(q2,bk,u2);
        w0=fmaf(k0,bq,w0); w1=fmaf(k1,bq,w1); w2=fmaf(k2,bq,w2);
        c0=fmaf(bq,bk,c0);
    }
    float vals[16] = {G00,G01,G02,u0, G10,G11,G12,u1, G20,G21,G22,u2, w0,w1,w2,c0};
    const float sc = 0.10206207261596577f; // 1/sqrt(96)
    #pragma unroll
    for (int q = 0; q < 16; ++q) {
        float v = vals[q];
        for (int off = 32; off; off >>= 1) v += __shfl_down(v, off);
        if (lane == 0) hGm[h*16 + q] = v * sc;
    }
}

// ---------------------------------------------------------------------------
// Tokenizer attention, 2-pass. One block per (segment, head, batch).
// ---------------------------------------------------------------------------
__global__ __launch_bounds__(256) void tok_attn_k(
    const float* __restrict__ img, const float* __restrict__ hGm,
    const float* __restrict__ W2, const float* __restrict__ b2,
    __hip_bfloat16* __restrict__ pooledb)
{
    int s = blockIdx.x, h = blockIdx.y, b = blockIdx.z;
    int t = threadIdx.x;
    __shared__ float4 pxm[256];
    __shared__ float4 ylds[256];
    __shared__ float  Ash[256];
    __shared__ float  tsum[3];

    int gy = s / 14, gx = s - gy*14;
    int row = gy*16 + (t >> 4), col = gx*16 + (t & 15);
    long base = ((long)b*3*224 + row)*224 + col;
    float p0 = img[base];
    float p1 = img[base + 224*224];
    float p2 = img[base + 2*224*224];

    const float4* M4 = reinterpret_cast<const float4*>(hGm) + h*4;
    float4 r0 = M4[0], r1 = M4[1], r2 = M4[2], r3 = M4[3];
    float y0 = fmaf(p0,r0.x, fmaf(p1,r0.y, fmaf(p2,r0.z, r0.w)));
    float y1 = fmaf(p0,r1.x, fmaf(p1,r1.y, fmaf(p2,r1.z, r1.w)));
    float y2 = fmaf(p0,r2.x, fmaf(p1,r2.y, fmaf(p2,r2.z, r2.w)));
    float y3 = fmaf(p0,r3.x, fmaf(p1,r3.y, fmaf(p2,r3.z, r3.w)));
    ylds[t] = make_float4(y0,y1,y2,y3);
    pxm[t]  = make_float4(p0,p1,p2,0.f);
    __syncthreads();

    float li = 0.f;
    #pragma unroll 4
    for (int j = 0; j < 256; ++j) {
        float4 Y = ylds[j];
        float scr = fmaf(p0,Y.x, fmaf(p1,Y.y, fmaf(p2,Y.z, Y.w)));
        li += __expf(scr);
    }
    pxm[t].w = -__logf(li);
    __syncthreads();

    float Aj = 0.f;
    #pragma unroll 4
    for (int i = 0; i < 256; ++i) {
        float4 q = pxm[i];
        float scr = fmaf(q.x,y0, fmaf(q.y,y1, fmaf(q.z,y2, y3))) + q.w;
        Aj += __expf(scr);
    }
    Ash[t] = Aj;
    __syncthreads();

    int w = t >> 6, lane = t & 63;
    if (w < 3) {
        float prt = 0.f;
        for (int j = lane; j < 256; j += 64) {
            const float* pj = reinterpret_cast<const float*>(&pxm[j]);
            prt = fmaf(Ash[j], pj[w], prt);
        }
        for (int off = 32; off; off >>= 1) prt += __shfl_down(prt, off);
        if (lane == 0) tsum[w] = prt;
    }
    __syncthreads();

    if (t < 96) {
        int o = 768 + h*96 + t;
        float v = (W2[o*3]*tsum[0] + W2[o*3+1]*tsum[1] + W2[o*3+2]*tsum[2]) * (1.f/256.f)
                  + b2[o];
        pooledb[((long)(b*196 + s))*384 + h*96 + t] = __float2bfloat16(v);
    }
}

// ---------------------------------------------------------------------------
// MFMA bf16 GEMM, 1 wave per block, 16x64 tile (tokenizer out-proj only).
// ---------------------------------------------------------------------------
__global__ __launch_bounds__(64) void gemm_mfma_k(
    const __hip_bfloat16* __restrict__ A, const __hip_bfloat16* __restrict__ W,
    const float* __restrict__ bias, float* __restrict__ C,
    int M, int N, int K, int lda, int ldw, int ldc)
{
    int l = threadIdx.x;
    int m0 = blockIdx.x * 16, n0 = blockIdx.y * 64;
    int arow = m0 + (l & 15); if (arow >= M) arow = M - 1;
    const __hip_bfloat16* Ap = A + (long)arow * lda + ((l >> 4) << 3);
    const __hip_bfloat16* W0 = W + (long)(n0 + (l & 15)) * ldw + ((l >> 4) << 3);
    long wst = (long)ldw * 16;

    f32x4 acc[4];
    #pragma unroll
    for (int f = 0; f < 4; ++f) acc[f] = f32x4{0.f,0.f,0.f,0.f};

    int niter = K >> 5;
    #pragma unroll 4
    for (int kt = 0; kt < niter; ++kt) {
        int k = kt << 5;
        short8b a  = *reinterpret_cast<const short8b*>(Ap + k);
        short8b b0 = *reinterpret_cast<const short8b*>(W0 + k);
        short8b b1 = *reinterpret_cast<const short8b*>(W0 + wst + k);
        short8b b2 = *reinterpret_cast<const short8b*>(W0 + 2*wst + k);
        short8b b3 = *reinterpret_cast<const short8b*>(W0 + 3*wst + k);
        acc[0] = __builtin_amdgcn_mfma_f32_16x16x32_bf16(a, b0, acc[0], 0, 0, 0);
        acc[1] = __builtin_amdgcn_mfma_f32_16x16x32_bf16(a, b1, acc[1], 0, 0, 0);
        acc[2] = __builtin_amdgcn_mfma_f32_16x16x32_bf16(a, b2, acc[2], 0, 0, 0);
        acc[3] = __builtin_amdgcn_mfma_f32_16x16x32_bf16(a, b3, acc[3], 0, 0, 0);
    }

    int cl = l & 15;
    int rbase = m0 + ((l >> 4) << 2);
    #pragma unroll
    for (int f = 0; f < 4; ++f) {
        int n = n0 + f*16 + cl;
        float bv = bias ? bias[n] : 0.f;
        #pragma unroll
        for (int r = 0; r < 4; ++r) {
            int m = rbase + r;
            if (m >= M) continue;
            C[(long)m*ldc + n] = acc[f][r] + bv;
        }
    }
}

// ---------------------------------------------------------------------------
// x0 = concat(cls, tok) + pos_embed
// ---------------------------------------------------------------------------
__global__ __launch_bounds__(256) void build_x0_k(
    const float* __restrict__ tok, const float* __restrict__ cls,
    const float* __restrict__ pos, float* __restrict__ x)
{
    int idx = blockIdx.x*256 + threadIdx.x;
    if (idx >= 2*197*384) return;
    int d = idx % 384;
    int n = (idx / 384) % 197;
    int b = idx / (384*197);
    float v = (n == 0) ? cls[d] : tok[((long)b*196 + (n-1))*384 + d];
    x[idx] = v + pos[n*384 + d];
}

// ---------------------------------------------------------------------------
// Two-level global barrier (256 blocks = 8 classes x 32).
// bar[c*64]: class counters; bar[512]: root; bar[576]: go flag.
// Monotonic counters; poll line separate from RMW lines.
// ---------------------------------------------------------------------------
static __device__ __forceinline__ void gbar(int* bar, int c, int rnd)
{
    __syncthreads();
    if (threadIdx.x == 0) {
        __threadfence();                            // release (agent)
        int old = atomicAdd(bar + c*64, 1);
        if (old == rnd*32 - 1) {                    // last arrival of class
            int ro = atomicAdd(bar + 512, 1);
            if (ro == rnd*8 - 1)                    // last class
                __hip_atomic_store(bar + 576, rnd, __ATOMIC_RELEASE,
                                   __HIP_MEMORY_SCOPE_AGENT);
        }
        while (__hip_atomic_load(bar + 576, __ATOMIC_RELAXED,
                                 __HIP_MEMORY_SCOPE_AGENT) < rnd)
            __builtin_amdgcn_s_sleep(8);
        __threadfence();                            // acquire (agent)
    }
    __syncthreads();
}

// ---------------------------------------------------------------------------
// MEGA persistent kernel: ViT trunk (12 layers) + final LN + head.
// 256 blocks x 256 threads, 1 block/CU. XCD-aware work mapping:
// class c = blockIdx&7 (assumed XCD), weight n-tiles nt = c (mod 8).
// ---------------------------------------------------------------------------
struct MegaArgs {
    float* x;
    const float *ln1_g, *ln1_b, *ln2_g, *ln2_b;
    const float *qkv_b, *proj_b, *fc1_b, *fc2_b;
    const __hip_bfloat16 *qkvwb, *projwb, *fc1wb, *fc2wb;
    __hip_bfloat16 *qb, *kb, *vT, *attnb, *hbufb;
    const float *norm_g, *norm_b, *head_w, *head_b;
    float* xnf;
    float* out;
    int* bar;
};

__global__ __launch_bounds__(256, 1) void mega_k(MegaArgs A)
{
    __shared__ __align__(16) short lp[4][16*232];
    int tid = threadIdx.x;
    int wid = tid >> 6, l = tid & 63;
    int c = blockIdx.x & 7;                     // XCD class
    int s = (blockIdx.x >> 3) * 4 + wid;        // slot within class, 0..127
    int cl = l & 15, hi = l >> 4;
    int rnd = 0;

    for (int layer = 0; layer < 12; ++layer) {
        const __hip_bfloat16* qkvw = A.qkvwb + (long)layer*1152*384;
        const __hip_bfloat16* projw = A.projwb + (long)layer*384*384;
        const __hip_bfloat16* fc1w = A.fc1wb + (long)layer*1536*384;
        const __hip_bfloat16* fc2w = A.fc2wb + (long)layer*384*1536;

        // ---- S1: LN1 + QKV (NT=18: nt = c+8j), scatter q/k/vT ----
        {
            int kc = (c < 2) ? 3 : 2;
            if (s < kc*25) {
                int nt = c + 8*(s/25);
                int mt = s % 25;
                int m0 = mt*16, n0 = nt*64;
                int row = m0 + cl; if (row >= 394) row = 393;
                const float* xp = A.x + (long)row*384 + (hi << 3);
                float sum = 0.f, sq = 0.f;
                #pragma unroll
                for (int t = 0; t < 12; ++t) {
                    float4 v0 = *reinterpret_cast<const float4*>(xp + t*32);
                    float4 v1 = *reinterpret_cast<const float4*>(xp + t*32 + 4);
                    sum += v0.x+v0.y+v0.z+v0.w + v1.x+v1.y+v1.z+v1.w;
                    sq  += v0.x*v0.x+v0.y*v0.y+v0.z*v0.z+v0.w*v0.w
                         + v1.x*v1.x+v1.y*v1.y+v1.z*v1.z+v1.w*v1.w;
                }
                sum += __shfl_xor(sum, 16); sum += __shfl_xor(sum, 32);
                sq  += __shfl_xor(sq, 16);  sq  += __shfl_xor(sq, 32);
                float mean = sum * (1.f/384.f);
                float var  = sq * (1.f/384.f) - mean*mean;
                float rstd = rsqrtf(var + 1e-6f);
                const float* g = A.ln1_g + layer*384;
                const float* b = A.ln1_b + layer*384;
                const __hip_bfloat16* Wp = qkvw + (long)(n0 + cl)*384 + (hi << 3);
                f32x4 acc[4];
                #pragma unroll
                for (int f = 0; f < 4; ++f) acc[f] = f32x4{0.f,0.f,0.f,0.f};
                #pragma unroll 2
                for (int t = 0; t < 12; ++t) {
                    int k = t*32 + (hi << 3);
                    float4 v0 = *reinterpret_cast<const float4*>(xp + t*32);
                    float4 v1 = *reinterpret_cast<const float4*>(xp + t*32 + 4);
                    float4 g0 = *reinterpret_cast<const float4*>(g + k);
                    float4 g1 = *reinterpret_cast<const float4*>(g + k + 4);
                    float4 bb0 = *reinterpret_cast<const float4*>(b + k);
                    float4 bb1 = *reinterpret_cast<const float4*>(b + k + 4);
                    short8b a;
                    a[0] = bf16s(fmaf((v0.x-mean)*rstd, g0.x, bb0.x));
                    a[1] = bf16s(fmaf((v0.y-mean)*rstd, g0.y, bb0.y));
                    a[2] = bf16s(fmaf((v0.z-mean)*rstd, g0.z, bb0.z));
                    a[3] = bf16s(fmaf((v0.w-mean)*rstd, g0.w, bb0.w));
                    a[4] = bf16s(fmaf((v1.x-mean)*rstd, g1.x, bb1.x));
                    a[5] = bf16s(fmaf((v1.y-mean)*rstd, g1.y, bb1.y));
                    a[6] = bf16s(fmaf((v1.z-mean)*rstd, g1.z, bb1.z));
                    a[7] = bf16s(fmaf((v1.w-mean)*rstd, g1.w, bb1.w));
                    short8b w0 = *reinterpret_cast<const short8b*>(Wp + t*32);
                    short8b w1 = *reinterpret_cast<const short8b*>(Wp + 16L*384 + t*32);
                    short8b w2 = *reinterpret_cast<const short8b*>(Wp + 32L*384 + t*32);
                    short8b w3 = *reinterpret_cast<const short8b*>(Wp + 48L*384 + t*32);
                    acc[0] = __builtin_amdgcn_mfma_f32_16x16x32_bf16(a, w0, acc[0], 0, 0, 0);
                    acc[1] = __builtin_amdgcn_mfma_f32_16x16x32_bf16(a, w1, acc[1], 0, 0, 0);
                    acc[2] = __builtin_amdgcn_mfma_f32_16x16x32_bf16(a, w2, acc[2], 0, 0, 0);
                    acc[3] = __builtin_amdgcn_mfma_f32_16x16x32_bf16(a, w3, acc[3], 0, 0, 0);
                }
                int rb = hi << 2;
                #pragma unroll
                for (int f = 0; f < 4; ++f) {
                    int n = n0 + f*16 + cl;
                    float bv = A.qkv_b[layer*1152 + n];
                    #pragma unroll
                    for (int r = 0; r < 4; ++r) {
                        int m = m0 + rb + r;
                        if (m >= 394) continue;
                        float v = acc[f][r] + bv;
                        int bb = (m >= 197) ? 1 : 0;
                        int tokr = m - bb*197;
                        if (n < 384) {
                            int h = n >> 6, ch = n & 63;
                            A.qb[((long)(bb*6 + h)*208 + tokr)*64 + ch] = __float2bfloat16(v * 0.125f);
                        } else if (n < 768) {
                            int nn = n - 384, h = nn >> 6, ch = nn & 63;
                            A.kb[((long)(bb*6 + h)*208 + tokr)*64 + ch] = __float2bfloat16(v);
                        } else {
                            int nn = n - 768, h = nn >> 6, ch = nn & 63;
                            A.vT[((long)(bb*6 + h)*64 + ch)*224 + tokr] = __float2bfloat16(v);
                        }
                    }
                }
            }
        }
        gbar(A.bar, c, ++rnd);

        // ---- S2: flash attention (12 bh: bh = c+8j) ----
        {
            int kc = (c < 4) ? 2 : 1;
            bool act = s < kc*13;
            short* lps = lp[wid];
            int bh = c + 8*(s/13);
            int qt = s % 13;
            if (act) {
                int q0 = qt * 16;
                if (l < 32) {
                    int prow = l >> 1, hf = l & 1;
                    *reinterpret_cast<int4*>(lps + prow*232 + 208 + hf*8) = int4{0,0,0,0};
                }
                const __hip_bfloat16* Qp = A.qb + ((long)bh*208 + q0 + cl)*64 + (hi << 3);
                const __hip_bfloat16* Kp = A.kb + ((long)bh*208 + cl)*64 + (hi << 3);
                f32x4 sc[13];
                #pragma unroll
                for (int f = 0; f < 13; ++f) sc[f] = f32x4{0.f,0.f,0.f,0.f};
                #pragma unroll
                for (int kt = 0; kt < 2; ++kt) {
                    short8b a = *reinterpret_cast<const short8b*>(Qp + kt*32);
                    #pragma unroll
                    for (int f = 0; f < 13; ++f) {
                        short8b kk = *reinterpret_cast<const short8b*>(Kp + (long)f*16*64 + kt*32);
                        sc[f] = __builtin_amdgcn_mfma_f32_16x16x32_bf16(a, kk, sc[f], 0, 0, 0);
                    }
                }
                if (cl >= 5) sc[12] = f32x4{-1e30f,-1e30f,-1e30f,-1e30f};
                #pragma unroll
                for (int r = 0; r < 4; ++r) {
                    float m = sc[0][r];
                    #pragma unroll
                    for (int f = 1; f < 13; ++f) m = fmaxf(m, sc[f][r]);
                    m = fmaxf(m, __shfl_xor(m, 1));
                    m = fmaxf(m, __shfl_xor(m, 2));
                    m = fmaxf(m, __shfl_xor(m, 4));
                    m = fmaxf(m, __shfl_xor(m, 8));
                    float e[13]; float ssum = 0.f;
                    #pragma unroll
                    for (int f = 0; f < 13; ++f) { e[f] = __expf(sc[f][r] - m); ssum += e[f]; }
                    ssum += __shfl_xor(ssum, 1);
                    ssum += __shfl_xor(ssum, 2);
                    ssum += __shfl_xor(ssum, 4);
                    ssum += __shfl_xor(ssum, 8);
                    float ri = 1.f / ssum;
                    int prow = (hi << 2) + r;
                    #pragma unroll
                    for (int f = 0; f < 13; ++f)
                        lps[prow*232 + f*16 + cl] = bf16s(e[f] * ri);
                }
            }
            __syncthreads();
            if (act) {
                int q0 = qt * 16;
                f32x4 o[4];
                #pragma unroll
                for (int f = 0; f < 4; ++f) o[f] = f32x4{0.f,0.f,0.f,0.f};
                const __hip_bfloat16* Vp = A.vT + ((long)bh*64 + cl)*224 + (hi << 3);
                #pragma unroll
                for (int kt = 0; kt < 7; ++kt) {
                    short8b pa = *reinterpret_cast<const short8b*>(&lps[cl*232 + (hi << 3) + kt*32]);
                    #pragma unroll
                    for (int f2 = 0; f2 < 4; ++f2) {
                        short8b vb = *reinterpret_cast<const short8b*>(Vp + (long)f2*16*224 + kt*32);
                        o[f2] = __builtin_amdgcn_mfma_f32_16x16x32_bf16(pa, vb, o[f2], 0, 0, 0);
                    }
                }
                int b = bh / 6, h = bh - b*6;
                #pragma unroll
                for (int f2 = 0; f2 < 4; ++f2) {
                    int ch = h*64 + f2*16 + cl;
                    #pragma unroll
                    for (int r = 0; r < 4; ++r) {
                        int qr = q0 + (hi << 2) + r;
                        if (qr < 197)
                            A.attnb[((long)(b*197 + qr))*384 + ch] = __float2bfloat16(o[f2][r]);
                    }
                }
            }
        }
        gbar(A.bar, c, ++rnd);

        // ---- S3: x += attn @ proj_w^T + proj_b (NT=6: nt = c, c<6) ----
        if (c < 6 && s < 25) {
            int nt = c, mt = s;
            int m0 = mt*16, n0 = nt*64;
            int arow = m0 + cl; if (arow >= 394) arow = 393;
            const __hip_bfloat16* Ap = A.attnb + (long)arow*384 + (hi << 3);
            const __hip_bfloat16* W0 = projw + (long)(n0 + cl)*384 + (hi << 3);
            f32x4 acc[4];
            #pragma unroll
            for (int f = 0; f < 4; ++f) acc[f] = f32x4{0.f,0.f,0.f,0.f};
            #pragma unroll 4
            for (int kt = 0; kt < 12; ++kt) {
                int k = kt << 5;
                short8b a  = *reinterpret_cast<const short8b*>(Ap + k);
                short8b b0 = *reinterpret_cast<const short8b*>(W0 + k);
                short8b b1 = *reinterpret_cast<const short8b*>(W0 + 16L*384 + k);
                short8b b2 = *reinterpret_cast<const short8b*>(W0 + 32L*384 + k);
                short8b b3 = *reinterpret_cast<const short8b*>(W0 + 48L*384 + k);
                acc[0] = __builtin_amdgcn_mfma_f32_16x16x32_bf16(a, b0, acc[0], 0, 0, 0);
                acc[1] = __builtin_amdgcn_mfma_f32_16x16x32_bf16(a, b1, acc[1], 0, 0, 0);
                acc[2] = __builtin_amdgcn_mfma_f32_16x16x32_bf16(a, b2, acc[2], 0, 0, 0);
                acc[3] = __builtin_amdgcn_mfma_f32_16x16x32_bf16(a, b3, acc[3], 0, 0, 0);
            }
            int rb = hi << 2;
            #pragma unroll
            for (int f = 0; f < 4; ++f) {
                int n = n0 + f*16 + cl;
                float bv = A.proj_b[layer*384 + n];
                #pragma unroll
                for (int r = 0; r < 4; ++r) {
                    int m = m0 + rb + r;
                    if (m >= 394) continue;
                    A.x[(long)m*384 + n] += acc[f][r] + bv;
                }
            }
        }
        gbar(A.bar, c, ++rnd);

        // ---- S4: LN2 + FC1 + gelu (NT=24: nt = c+8j, j<3) ----
        if (s < 75) {
            int nt = c + 8*(s/25);
            int mt = s % 25;
            int m0 = mt*16, n0 = nt*64;
            int row = m0 + cl; if (row >= 394) row = 393;
            const float* xp = A.x + (long)row*384 + (hi << 3);
            float sum = 0.f, sq = 0.f;
            #pragma unroll
            for (int t = 0; t < 12; ++t) {
                float4 v0 = *reinterpret_cast<const float4*>(xp + t*32);
                float4 v1 = *reinterpret_cast<const float4*>(xp + t*32 + 4);
                sum += v0.x+v0.y+v0.z+v0.w + v1.x+v1.y+v1.z+v1.w;
                sq  += v0.x*v0.x+v0.y*v0.y+v0.z*v0.z+v0.w*v0.w
                     + v1.x*v1.x+v1.y*v1.y+v1.z*v1.z+v1.w*v1.w;
            }
            sum += __shfl_xor(sum, 16); sum += __shfl_xor(sum, 32);
            sq  += __shfl_xor(sq, 16);  sq  += __shfl_xor(sq, 32);
            float mean = sum * (1.f/384.f);
            float var  = sq * (1.f/384.f) - mean*mean;
            float rstd = rsqrtf(var + 1e-6f);
            const float* g = A.ln2_g + layer*384;
            const float* b = A.ln2_b + layer*384;
            const __hip_bfloat16* Wp = fc1w + (long)(n0 + cl)*384 + (hi << 3);
            f32x4 acc[4];
            #pragma unroll
            for (int f = 0; f < 4; ++f) acc[f] = f32x4{0.f,0.f,0.f,0.f};
            #pragma unroll 2
            for (int t = 0; t < 12; ++t) {
                int k = t*32 + (hi << 3);
                float4 v0 = *reinterpret_cast<const float4*>(xp + t*32);
                float4 v1 = *reinterpret_cast<const float4*>(xp + t*32 + 4);
                float4 g0 = *reinterpret_cast<const float4*>(g + k);
                float4 g1 = *reinterpret_cast<const float4*>(g + k + 4);
                float4 bb0 = *reinterpret_cast<const float4*>(b + k);
                float4 bb1 = *reinterpret_cast<const float4*>(b + k + 4);
                short8b a;
                a[0] = bf16s(fmaf((v0.x-mean)*rstd, g0.x, bb0.x));
                a[1] = bf16s(fmaf((v0.y-mean)*rstd, g0.y, bb0.y));
                a[2] = bf16s(fmaf((v0.z-mean)*rstd, g0.z, bb0.z));
                a[3] = bf16s(fmaf((v0.w-mean)*rstd, g0.w, bb0.w));
                a[4] = bf16s(fmaf((v1.x-mean)*rstd, g1.x, bb1.x));
                a[5] = bf16s(fmaf((v1.y-mean)*rstd, g1.y, bb1.y));
                a[6] = bf16s(fmaf((v1.z-mean)*rstd, g1.z, bb1.z));
                a[7] = bf16s(fmaf((v1.w-mean)*rstd, g1.w, bb1.w));
                short8b w0 = *reinterpret_cast<const short8b*>(Wp + t*32);
                short8b w1 = *reinterpret_cast<const short8b*>(Wp + 16L*384 + t*32);
                short8b w2 = *reinterpret_cast<const short8b*>(Wp + 32L*384 + t*32);
                short8b w3 = *reinterpret_cast<const short8b*>(Wp + 48L*384 + t*32);
                acc[0] = __builtin_amdgcn_mfma_f32_16x16x32_bf16(a, w0, acc[0], 0, 0, 0);
                acc[1] = __builtin_amdgcn_mfma_f32_16x16x32_bf16(a, w1, acc[1], 0, 0, 0);
                acc[2] = __builtin_amdgcn_mfma_f32_16x16x32_bf16(a, w2, acc[2], 0, 0, 0);
                acc[3] = __builtin_amdgcn_mfma_f32_16x16x32_bf16(a, w3, acc[3], 0, 0, 0);
            }
            int rb = hi << 2;
            #pragma unroll
            for (int f = 0; f < 4; ++f) {
                int n = n0 + f*16 + cl;
                float bv = A.fc1_b[layer*1536 + n];
                #pragma unroll
                for (int r = 0; r < 4; ++r) {
                    int m = m0 + rb + r;
                    if (m >= 394) continue;
                    A.hbufb[(long)m*1536 + n] = __float2bfloat16(gelu_exact(acc[f][r] + bv));
                }
            }
        }
        gbar(A.bar, c, ++rnd);

        // ---- S5: x += hbuf @ fc2_w^T + fc2_b (NT=6: nt = c, c<6) ----
        if (c < 6 && s < 25) {
            int nt = c, mt = s;
            int m0 = mt*16, n0 = nt*64;
            int arow = m0 + cl; if (arow >= 394) arow = 393;
            const __hip_bfloat16* Ap = A.hbufb + (long)arow*1536 + (hi << 3);
            const __hip_bfloat16* W0 = fc2w + (long)(n0 + cl)*1536 + (hi << 3);
            f32x4 acc[4];
            #pragma unroll
            for (int f = 0; f < 4; ++f) acc[f] = f32x4{0.f,0.f,0.f,0.f};
            #pragma unroll 4
            for (int kt = 0; kt < 48; ++kt) {
                int k = kt << 5;
                short8b a  = *reinterpret_cast<const short8b*>(Ap + k);
                short8b b0 = *reinterpret_cast<const short8b*>(W0 + k);
                short8b b1 = *reinterpret_cast<const short8b*>(W0 + 16L*1536 + k);
                short8b b2 = *reinterpret_cast<const short8b*>(W0 + 32L*1536 + k);
                short8b b3 = *reinterpret_cast<const short8b*>(W0 + 48L*1536 + k);
                acc[0] = __builtin_amdgcn_mfma_f32_16x16x32_bf16(a, b0, acc[0], 0, 0, 0);
                acc[1] = __builtin_amdgcn_mfma_f32_16x16x32_bf16(a, b1, acc[1], 0, 0, 0);
                acc[2] = __builtin_amdgcn_mfma_f32_16x16x32_bf16(a, b2, acc[2], 0, 0, 0);
                acc[3] = __builtin_amdgcn_mfma_f32_16x16x32_bf16(a, b3, acc[3], 0, 0, 0);
            }
            int rb = hi << 2;
            #pragma unroll
            for (int f = 0; f < 4; ++f) {
                int n = n0 + f*16 + cl;
                float bv = A.fc2_b[layer*384 + n];
                #pragma unroll
                for (int r = 0; r < 4; ++r) {
                    int m = m0 + rb + r;
                    if (m >= 394) continue;
                    A.x[(long)m*384 + n] += acc[f][r] + bv;
                }
            }
        }
        gbar(A.bar, c, ++rnd);
    }

    int gw2 = c * 128 + s;

    // ---- S6: final LN -> xnf (f32) ----
    if (gw2 < 25) {
        int m0 = gw2 * 16;
        int row = m0 + cl; if (row >= 394) row = 393;
        const float* xp = A.x + (long)row*384 + (hi << 3);
        float sum = 0.f, sq = 0.f;
        #pragma unroll
        for (int t = 0; t < 12; ++t) {
            float4 v0 = *reinterpret_cast<const float4*>(xp + t*32);
            float4 v1 = *reinterpret_cast<const float4*>(xp + t*32 + 4);
            sum += v0.x+v0.y+v0.z+v0.w + v1.x+v1.y+v1.z+v1.w;
            sq  += v0.x*v0.x+v0.y*v0.y+v0.z*v0.z+v0.w*v0.w
                 + v1.x*v1.x+v1.y*v1.y+v1.z*v1.z+v1.w*v1.w;
        }
        sum += __shfl_xor(sum, 16); sum += __shfl_xor(sum, 32);
        sq  += __shfl_xor(sq, 16);  sq  += __shfl_xor(sq, 32);
        float mean = sum * (1.f/384.f);
        float var  = sq * (1.f/384.f) - mean*mean;
        float rstd = rsqrtf(var + 1e-6f);
        if (m0 + cl < 394) {
            float* yp = A.xnf + (long)(m0 + cl)*384 + (hi << 3);
            #pragma unroll
            for (int t = 0; t < 12; ++t) {
                int k = t*32 + (hi << 3);
                float4 v0 = *reinterpret_cast<const float4*>(xp + t*32);
                float4 v1 = *reinterpret_cast<const float4*>(xp + t*32 + 4);
                float4 o0, o1;
                o0.x = fmaf((v0.x-mean)*rstd, A.norm_g[k+0], A.norm_b[k+0]);
                o0.y = fmaf((v0.y-mean)*rstd, A.norm_g[k+1], A.norm_b[k+1]);
                o0.z = fmaf((v0.z-mean)*rstd, A.norm_g[k+2], A.norm_b[k+2]);
                o0.w = fmaf((v0.w-mean)*rstd, A.norm_g[k+3], A.norm_b[k+3]);
                o1.x = fmaf((v1.x-mean)*rstd, A.norm_g[k+4], A.norm_b[k+4]);
                o1.y = fmaf((v1.y-mean)*rstd, A.norm_g[k+5], A.norm_b[k+5]);
                o1.z = fmaf((v1.z-mean)*rstd, A.norm_g[k+6], A.norm_b[k+6]);
                o1.w = fmaf((v1.w-mean)*rstd, A.norm_g[k+7], A.norm_b[k+7]);
                *reinterpret_cast<float4*>(yp + t*32) = o0;
                *reinterpret_cast<float4*>(yp + t*32 + 4) = o1;
            }
        }
    }
    gbar(A.bar, c, ++rnd);

    // ---- S7: head out[2][1000] ----
    {
        int idx = gw2 * 64 + l;
        if (idx < 2000) {
            int m = idx / 1000, n = idx - m*1000;
            const float* xr = A.xnf + (long)(m*197)*384;
            const float* wr = A.head_w + (long)n*384;
            float accv = A.head_b[n];
            for (int d = 0; d < 384; d += 4) {
                float4 xv = *reinterpret_cast<const float4*>(xr + d);
                float4 wv = *reinterpret_cast<const float4*>(wr + d);
                accv = fmaf(xv.x,wv.x, fmaf(xv.y,wv.y, fmaf(xv.z,wv.z, fmaf(xv.w,wv.w, accv))));
            }
            A.out[m*1000 + n] = accv;
        }
    }
}

// ---------------------------------------------------------------------------
extern "C" void kernel_launch(void* const* d_in, const int* in_sizes, int n_in,
                              void* d_out, int out_size, void* d_ws, size_t ws_size,
                              hipStream_t stream)
{
    const float* img      = (const float*)d_in[0];
    const float* fp_w     = (const float*)d_in[2];
    const float* fp_b     = (const float*)d_in[3];
    const float* ap_in_w  = (const float*)d_in[4];
    const float* ap_in_b  = (const float*)d_in[5];
    const float* ap_out_w = (const float*)d_in[6];
    const float* ap_out_b = (const float*)d_in[7];
    const float* cls_tok  = (const float*)d_in[8];
    const float* pos_emb  = (const float*)d_in[9];
    const float* ln1_g    = (const float*)d_in[10];
    const float* ln1_b    = (const float*)d_in[11];
    const float* qkv_w    = (const float*)d_in[12];
    const float* qkv_b    = (const float*)d_in[13];
    const float* proj_w   = (const float*)d_in[14];
    const float* proj_b   = (const float*)d_in[15];
    const float* ln2_g    = (const float*)d_in[16];
    const float* ln2_b    = (const float*)d_in[17];
    const float* fc1_w    = (const float*)d_in[18];
    const float* fc1_b    = (const float*)d_in[19];
    const float* fc2_w    = (const float*)d_in[20];
    const float* fc2_b    = (const float*)d_in[21];
    const float* norm_g   = (const float*)d_in[22];
    const float* norm_b   = (const float*)d_in[23];
    const float* head_w   = (const float*)d_in[24];
    const float* head_b   = (const float*)d_in[25];
    (void)in_sizes; (void)n_in; (void)out_size; (void)ws_size;
    float* out = (float*)d_out;

    float* ws = (float*)d_ws;
    size_t off = 0;
    auto alloc = [&](size_t nfl) { float* p = ws + off; off += (nfl + 63) & ~(size_t)63; return p; };
    float* W2     = alloc(1152*3);
    float* b2     = alloc(1152);
    float* hGm    = alloc(64);
    float* tok    = alloc(392L*384);
    float* x      = alloc(394L*384);
    float* xnf    = alloc(394L*384);
    int*   bar    = (int*)alloc(1024);
    __hip_bfloat16* pooledb = (__hip_bfloat16*)alloc(392L*384/2);
    __hip_bfloat16* attnb   = (__hip_bfloat16*)alloc(394L*384/2 + 64);
    __hip_bfloat16* hbufb   = (__hip_bfloat16*)alloc(394L*1536/2 + 64);
    __hip_bfloat16* qb      = (__hip_bfloat16*)alloc(12L*208*64/2);
    __hip_bfloat16* kb      = (__hip_bfloat16*)alloc(12L*208*64/2);
    __hip_bfloat16* vT      = (__hip_bfloat16*)alloc(12L*64*224/2);
    __hip_bfloat16* qkvwb   = (__hip_bfloat16*)alloc(12L*1152*384/2);
    __hip_bfloat16* projwb  = (__hip_bfloat16*)alloc(12L*384*384/2);
    __hip_bfloat16* fc1wb   = (__hip_bfloat16*)alloc(12L*1536*384/2);
    __hip_bfloat16* fc2wb   = (__hip_bfloat16*)alloc(12L*384*1536/2);
    __hip_bfloat16* apoutwb = (__hip_bfloat16*)alloc(384L*384/2);

    // ---- weight conversion + pad/barrier init ----
    {
        int n1 = 12*1152*384, n2 = 12*384*384, n3 = 12*1536*384, n4 = 384*384;
        cvt_bf16_k<<<(n1/4 + 255)/256, 256, 0, stream>>>(qkv_w,  qkvwb,  n1);
        cvt_bf16_k<<<(n2/4 + 255)/256, 256, 0, stream>>>(proj_w, projwb, n2);
        cvt_bf16_k<<<(n3/4 + 255)/256, 256, 0, stream>>>(fc1_w,  fc1wb,  n3);
        cvt_bf16_k<<<(n3/4 + 255)/256, 256, 0, stream>>>(fc2_w,  fc2wb,  n3);
        cvt_bf16_k<<<(n4/4 + 255)/256, 256, 0, stream>>>(ap_out_w, apoutwb, n4);
        init_k<<<(12*64*27 + 255)/256, 256, 0, stream>>>(vT, bar);
    }

    // ---- tokenizer ----
    prep_w2_k<<<5, 256, 0, stream>>>(ap_in_w, ap_in_b, fp_w, fp_b, W2, b2);
    prep_head_k<<<4, 64, 0, stream>>>(W2, b2, hGm);
    tok_attn_k<<<dim3(196,4,2), 256, 0, stream>>>(img, hGm, W2, b2, pooledb);
    gemm_mfma_k<<<dim3(25,6), 64, 0, stream>>>(
        pooledb, apoutwb, ap_out_b, tok, 392, 384, 384, 384, 384, 384);
    build_x0_k<<<(2*197*384 + 255)/256, 256, 0, stream>>>(tok, cls_tok, pos_emb, x);

    // ---- trunk + head: one persistent kernel, two-level barrier ----
    MegaArgs ma;
    ma.x = x;
    ma.ln1_g = ln1_g; ma.ln1_b = ln1_b; ma.ln2_g = ln2_g; ma.ln2_b = ln2_b;
    ma.qkv_b = qkv_b; ma.proj_b = proj_b; ma.fc1_b = fc1_b; ma.fc2_b = fc2_b;
    ma.qkvwb = qkvwb; ma.projwb = projwb; ma.fc1wb = fc1wb; ma.fc2wb = fc2wb;
    ma.qb = qb; ma.kb = kb; ma.vT = vT; ma.attnb = attnb; ma.hbufb = hbufb;
    ma.norm_g = norm_g; ma.norm_b = norm_b; ma.head_w = head_w; ma.head_b = head_b;
    ma.xnf = xnf; ma.out = out; ma.bar = bar;
    mega_k<<<256, 256, 0, stream>>>(ma);
}

// Round 7
// 1890.776 us; speedup vs baseline: 2.1028x; 1.0300x over previous
//
#include <hip/hip_runtime.h>
#include <hip/hip_bf16.h>
#include <math.h>

// ---------------------------------------------------------------------------
// Model dims: B=2, Cn=3, HI=WI=224, S=196, P=256, D=384, H_TOK=4
// DEPTH=12, H_VIT=6 (dh=64), HID=1536, NCLS=1000
// Token rows padded to TOKP=208 per batch; x layout [2][208][384] f32.
// ---------------------------------------------------------------------------
#define TOKP 208

typedef __attribute__((ext_vector_type(8))) short short8b;
typedef __attribute__((ext_vector_type(4))) float f32x4;

static __device__ __forceinline__ float gelu_exact(float v) {
    return 0.5f * v * (1.0f + erff(v * 0.70710678118654752440f));
}
static __device__ __forceinline__ short bf16s(float f) {
    __hip_bfloat16 h = __float2bfloat16(f);
    return *reinterpret_cast<short*>(&h);
}

// ---------------------------------------------------------------------------
__global__ __launch_bounds__(256) void cvt_bf16_k(
    const float* __restrict__ src, __hip_bfloat16* __restrict__ dst, int n)
{
    int i = (blockIdx.x * 256 + threadIdx.x) * 4;
    if (i >= n) return;
    float4 v = *reinterpret_cast<const float4*>(src + i);
    dst[i+0] = __float2bfloat16(v.x);
    dst[i+1] = __float2bfloat16(v.y);
    dst[i+2] = __float2bfloat16(v.z);
    dst[i+3] = __float2bfloat16(v.w);
}

// zero vT key-pad cols 208..223 for all [12][64] rows
__global__ __launch_bounds__(256) void init_k(__hip_bfloat16* __restrict__ vT)
{
    int i = blockIdx.x * 256 + threadIdx.x;
    if (i >= 12*64*16) return;
    int c = i & 15, r = i >> 4;
    vT[(long)r*224 + 208 + c] = __float2bfloat16(0.f);
}

// ---------------------------------------------------------------------------
__global__ __launch_bounds__(256) void prep_w2_k(
    const float* __restrict__ ap_in_w, const float* __restrict__ ap_in_b,
    const float* __restrict__ fp_w, const float* __restrict__ fp_b,
    float* __restrict__ W2, float* __restrict__ b2)
{
    int o = blockIdx.x * 256 + threadIdx.x;
    if (o >= 1152) return;
    const float* ar = ap_in_w + (long)o * 384;
    float a0 = 0.f, a1 = 0.f, a2 = 0.f, ab = ap_in_b[o];
    for (int d = 0; d < 384; ++d) {
        float aw = ar[d];
        a0 = fmaf(aw, fp_w[d*3+0], a0);
        a1 = fmaf(aw, fp_w[d*3+1], a1);
        a2 = fmaf(aw, fp_w[d*3+2], a2);
        ab = fmaf(aw, fp_b[d], ab);
    }
    W2[o*3+0] = a0; W2[o*3+1] = a1; W2[o*3+2] = a2; b2[o] = ab;
}

__global__ __launch_bounds__(64) void prep_head_k(
    const float* __restrict__ W2, const float* __restrict__ b2,
    float* __restrict__ hGm)
{
    int h = blockIdx.x;
    int lane = threadIdx.x;
    float G00=0,G01=0,G02=0,G10=0,G11=0,G12=0,G20=0,G21=0,G22=0;
    float u0=0,u1=0,u2=0,w0=0,w1=0,w2=0,c0=0;
    for (int d = lane; d < 96; d += 64) {
        int oq = h*96 + d, ok = 384 + h*96 + d;
        float q0=W2[oq*3],q1=W2[oq*3+1],q2=W2[oq*3+2];
        float k0=W2[ok*3],k1=W2[ok*3+1],k2=W2[ok*3+2];
        float bq=b2[oq], bk=b2[ok];
        G00=fmaf(q0,k0,G00); G01=fmaf(q0,k1,G01); G02=fmaf(q0,k2,G02);
        G10=fmaf(q1,k0,G10); G11=fmaf(q1,k1,G11); G12=fmaf(q1,k2,G12);
        G20=fmaf(q2,k0,G20); G21=fmaf(q2,k1,G21); G22=fmaf(q2,k2,G22);
        u0=fmaf(q0,bk,u0); u1=fmaf(q1,bk,u1); u2=fmaf(q2,bk,u2);
        w0=fmaf(k0,bq,w0); w1=fmaf(k1,bq,w1); w2=fmaf(k2,bq,w2);
        c0=fmaf(bq,bk,c0);
    }
    float vals[16] = {G00,G01,G02,u0, G10,G11,G12,u1, G20,G21,G22,u2, w0,w1,w2,c0};
    const float sc = 0.10206207261596577f; // 1/sqrt(96)
    #pragma unroll
    for (int q = 0; q < 16; ++q) {
        float v = vals[q];
        for (int off = 32; off; off >>= 1) v += __shfl_down(v, off);
        if (lane == 0) hGm[h*16 + q] = v * sc;
    }
}

// ---------------------------------------------------------------------------
// Tokenizer attention, 2-pass (validated R5/R6).
// ---------------------------------------------------------------------------
__global__ __launch_bounds__(256) void tok_attn_k(
    const float* __restrict__ img, const float* __restrict__ hGm,
    const float* __restrict__ W2, const float* __restrict__ b2,
    __hip_bfloat16* __restrict__ pooledb)
{
    int s = blockIdx.x, h = blockIdx.y, b = blockIdx.z;
    int t = threadIdx.x;
    __shared__ float4 pxm[256];
    __shared__ float4 ylds[256];
    __shared__ float  Ash[256];
    __shared__ float  tsum[3];

    int gy = s / 14, gx = s - gy*14;
    int row = gy*16 + (t >> 4), col = gx*16 + (t & 15);
    long base = ((long)b*3*224 + row)*224 + col;
    float p0 = img[base];
    float p1 = img[base + 224*224];
    float p2 = img[base + 2*224*224];

    const float4* M4 = reinterpret_cast<const float4*>(hGm) + h*4;
    float4 r0 = M4[0], r1 = M4[1], r2 = M4[2], r3 = M4[3];
    float y0 = fmaf(p0,r0.x, fmaf(p1,r0.y, fmaf(p2,r0.z, r0.w)));
    float y1 = fmaf(p0,r1.x, fmaf(p1,r1.y, fmaf(p2,r1.z, r1.w)));
    float y2 = fmaf(p0,r2.x, fmaf(p1,r2.y, fmaf(p2,r2.z, r2.w)));
    float y3 = fmaf(p0,r3.x, fmaf(p1,r3.y, fmaf(p2,r3.z, r3.w)));
    ylds[t] = make_float4(y0,y1,y2,y3);
    pxm[t]  = make_float4(p0,p1,p2,0.f);
    __syncthreads();

    float li = 0.f;
    #pragma unroll 4
    for (int j = 0; j < 256; ++j) {
        float4 Y = ylds[j];
        float scr = fmaf(p0,Y.x, fmaf(p1,Y.y, fmaf(p2,Y.z, Y.w)));
        li += __expf(scr);
    }
    pxm[t].w = -__logf(li);
    __syncthreads();

    float Aj = 0.f;
    #pragma unroll 4
    for (int i = 0; i < 256; ++i) {
        float4 q = pxm[i];
        float scr = fmaf(q.x,y0, fmaf(q.y,y1, fmaf(q.z,y2, y3))) + q.w;
        Aj += __expf(scr);
    }
    Ash[t] = Aj;
    __syncthreads();

    int w = t >> 6, lane = t & 63;
    if (w < 3) {
        float prt = 0.f;
        for (int j = lane; j < 256; j += 64) {
            const float* pj = reinterpret_cast<const float*>(&pxm[j]);
            prt = fmaf(Ash[j], pj[w], prt);
        }
        for (int off = 32; off; off >>= 1) prt += __shfl_down(prt, off);
        if (lane == 0) tsum[w] = prt;
    }
    __syncthreads();

    if (t < 96) {
        int o = 768 + h*96 + t;
        float v = (W2[o*3]*tsum[0] + W2[o*3+1]*tsum[1] + W2[o*3+2]*tsum[2]) * (1.f/256.f)
                  + b2[o];
        pooledb[((long)(b*196 + s))*384 + h*96 + t] = __float2bfloat16(v);
    }
}

// ---------------------------------------------------------------------------
// MFMA bf16 GEMM, 1 wave per block (tokenizer out-proj only).
// ---------------------------------------------------------------------------
__global__ __launch_bounds__(64) void gemm_mfma_k(
    const __hip_bfloat16* __restrict__ A, const __hip_bfloat16* __restrict__ W,
    const float* __restrict__ bias, float* __restrict__ C,
    int M, int N, int K, int lda, int ldw, int ldc)
{
    int l = threadIdx.x;
    int m0 = blockIdx.x * 16, n0 = blockIdx.y * 64;
    int arow = m0 + (l & 15); if (arow >= M) arow = M - 1;
    const __hip_bfloat16* Ap = A + (long)arow * lda + ((l >> 4) << 3);
    const __hip_bfloat16* W0 = W + (long)(n0 + (l & 15)) * ldw + ((l >> 4) << 3);
    long wst = (long)ldw * 16;

    f32x4 acc[4];
    #pragma unroll
    for (int f = 0; f < 4; ++f) acc[f] = f32x4{0.f,0.f,0.f,0.f};

    int niter = K >> 5;
    #pragma unroll 4
    for (int kt = 0; kt < niter; ++kt) {
        int k = kt << 5;
        short8b a  = *reinterpret_cast<const short8b*>(Ap + k);
        short8b b0 = *reinterpret_cast<const short8b*>(W0 + k);
        short8b b1 = *reinterpret_cast<const short8b*>(W0 + wst + k);
        short8b b2 = *reinterpret_cast<const short8b*>(W0 + 2*wst + k);
        short8b b3 = *reinterpret_cast<const short8b*>(W0 + 3*wst + k);
        acc[0] = __builtin_amdgcn_mfma_f32_16x16x32_bf16(a, b0, acc[0], 0, 0, 0);
        acc[1] = __builtin_amdgcn_mfma_f32_16x16x32_bf16(a, b1, acc[1], 0, 0, 0);
        acc[2] = __builtin_amdgcn_mfma_f32_16x16x32_bf16(a, b2, acc[2], 0, 0, 0);
        acc[3] = __builtin_amdgcn_mfma_f32_16x16x32_bf16(a, b3, acc[3], 0, 0, 0);
    }

    int cl = l & 15;
    int rbase = m0 + ((l >> 4) << 2);
    #pragma unroll
    for (int f = 0; f < 4; ++f) {
        int n = n0 + f*16 + cl;
        float bv = bias ? bias[n] : 0.f;
        #pragma unroll
        for (int r = 0; r < 4; ++r) {
            int m = rbase + r;
            if (m >= M) continue;
            C[(long)m*ldc + n] = acc[f][r] + bv;
        }
    }
}

// ---------------------------------------------------------------------------
// x0[2][208][384]: rows 0..196 = concat(cls,tok)+pos; rows 197..207 = 0
// ---------------------------------------------------------------------------
__global__ __launch_bounds__(256) void build_x0_k(
    const float* __restrict__ tok, const float* __restrict__ cls,
    const float* __restrict__ pos, float* __restrict__ x)
{
    int idx = blockIdx.x*256 + threadIdx.x;
    if (idx >= 2*TOKP*384) return;
    int d = idx % 384;
    int n = (idx / 384) % TOKP;
    int b = idx / (384*TOKP);
    float v = 0.f;
    if (n == 0)       v = cls[d] + pos[d];
    else if (n < 197) v = tok[((long)b*196 + (n-1))*384 + d] + pos[n*384 + d];
    x[idx] = v;
}

// ---------------------------------------------------------------------------
// LAYER KERNEL: 26 blocks (2 batches x 13 row-tiles) x 256 threads (4 waves).
// MODE 0: LN1(layer0) + QKV scatter only (prologue).
// MODE 1: attn -> proj+res -> LN2 -> fc1+gelu -> fc2+res -> LN1next -> QKV.
// MODE 2: same but stops after fc2+res (last layer).
// ---------------------------------------------------------------------------
template<int MODE>
__global__ __launch_bounds__(256, 1) void layer_k(
    float* __restrict__ x,
    __hip_bfloat16* __restrict__ qb, __hip_bfloat16* __restrict__ kb,
    __hip_bfloat16* __restrict__ vT,
    const __hip_bfloat16* __restrict__ projw, const float* __restrict__ projb,
    const float* __restrict__ ln2g, const float* __restrict__ ln2b,
    const __hip_bfloat16* __restrict__ fc1w, const float* __restrict__ fc1b,
    const __hip_bfloat16* __restrict__ fc2w, const float* __restrict__ fc2b,
    const float* __restrict__ ln1g, const float* __restrict__ ln1b,
    const __hip_bfloat16* __restrict__ qkvw, const float* __restrict__ qkvb)
{
    __shared__ __align__(16) short lp[4*16*232];    // per-wave P tiles
    __shared__ __align__(16) short xnS[16*392];     // attn-out / LN'd row band
    __shared__ __align__(16) short hbS[16*1544];    // fc1 output band
    __shared__ float redS[4][16], redQ[4][16];

    int tid = threadIdx.x, wid = tid >> 6, l = tid & 63;
    int cl = l & 15, hi = l >> 4;
    int bt = blockIdx.x, b = bt / 13, mt = bt - b*13;
    int tokr0 = mt * 16;
    long growbase = (long)(b*TOKP + tokr0);
    int rb = hi << 2;

    float resv[6][4];   // x_after_attn (this wave's 96 cols), MODE 1/2

    if (MODE != 0) {
        // ================= A1: attention =================
        short* lps = lp + wid*16*232;
        if (l < 32) {
            int pr = l >> 1, hf = l & 1;
            *reinterpret_cast<int4*>(lps + pr*232 + 208 + hf*8) = int4{0,0,0,0};
        }
        int b6 = b*6;
        for (int hh = 0; hh < 2; ++hh) {
            int h = wid + hh*4;
            if (h < 6) {
                int bh = b6 + h;
                const __hip_bfloat16* Qp = qb + ((long)bh*TOKP + tokr0 + cl)*64 + (hi<<3);
                const __hip_bfloat16* Kp = kb + ((long)bh*TOKP + cl)*64 + (hi<<3);
                f32x4 s[13];
                #pragma unroll
                for (int f = 0; f < 13; ++f) s[f] = f32x4{0.f,0.f,0.f,0.f};
                #pragma unroll
                for (int kt = 0; kt < 2; ++kt) {
                    short8b a = *reinterpret_cast<const short8b*>(Qp + kt*32);
                    #pragma unroll
                    for (int f = 0; f < 13; ++f) {
                        short8b kk = *reinterpret_cast<const short8b*>(Kp + (long)f*16*64 + kt*32);
                        s[f] = __builtin_amdgcn_mfma_f32_16x16x32_bf16(a, kk, s[f], 0, 0, 0);
                    }
                }
                if (cl >= 5) s[12] = f32x4{-1e30f,-1e30f,-1e30f,-1e30f};
                #pragma unroll
                for (int r = 0; r < 4; ++r) {
                    float m = s[0][r];
                    #pragma unroll
                    for (int f = 1; f < 13; ++f) m = fmaxf(m, s[f][r]);
                    m = fmaxf(m, __shfl_xor(m, 1));
                    m = fmaxf(m, __shfl_xor(m, 2));
                    m = fmaxf(m, __shfl_xor(m, 4));
                    m = fmaxf(m, __shfl_xor(m, 8));
                    float e[13]; float ssum = 0.f;
                    #pragma unroll
                    for (int f = 0; f < 13; ++f) { e[f] = __expf(s[f][r] - m); ssum += e[f]; }
                    ssum += __shfl_xor(ssum, 1);
                    ssum += __shfl_xor(ssum, 2);
                    ssum += __shfl_xor(ssum, 4);
                    ssum += __shfl_xor(ssum, 8);
                    float ri = 1.f / ssum;
                    int prow = rb + r;
                    #pragma unroll
                    for (int f = 0; f < 13; ++f)
                        lps[prow*232 + f*16 + cl] = bf16s(e[f] * ri);
                }
                asm volatile("s_waitcnt lgkmcnt(0)" ::: "memory");
                f32x4 o[4];
                #pragma unroll
                for (int f = 0; f < 4; ++f) o[f] = f32x4{0.f,0.f,0.f,0.f};
                const __hip_bfloat16* Vp = vT + ((long)bh*64 + cl)*224 + (hi<<3);
                #pragma unroll
                for (int kt = 0; kt < 7; ++kt) {
                    short8b pa = *reinterpret_cast<const short8b*>(lps + cl*232 + (hi<<3) + kt*32);
                    #pragma unroll
                    for (int f2 = 0; f2 < 4; ++f2) {
                        short8b vb = *reinterpret_cast<const short8b*>(Vp + (long)f2*16*224 + kt*32);
                        o[f2] = __builtin_amdgcn_mfma_f32_16x16x32_bf16(pa, vb, o[f2], 0, 0, 0);
                    }
                }
                #pragma unroll
                for (int f2 = 0; f2 < 4; ++f2)
                    #pragma unroll
                    for (int r = 0; r < 4; ++r)
                        xnS[(rb + r)*392 + h*64 + f2*16 + cl] = bf16s(o[f2][r]);
            }
        }
        __syncthreads();   // attnS (in xnS) complete

        // ================= A2: proj + residual + LN2 =================
        {
            int n0 = wid*96;
            f32x4 acc[6];
            #pragma unroll
            for (int f = 0; f < 6; ++f) acc[f] = f32x4{0.f,0.f,0.f,0.f};
            const __hip_bfloat16* W0 = projw + (long)(n0 + cl)*384 + (hi<<3);
            for (int kt = 0; kt < 12; ++kt) {
                short8b a = *reinterpret_cast<const short8b*>(xnS + cl*392 + kt*32 + (hi<<3));
                #pragma unroll
                for (int f = 0; f < 6; ++f) {
                    short8b wf = *reinterpret_cast<const short8b*>(W0 + (long)f*16*384 + kt*32);
                    acc[f] = __builtin_amdgcn_mfma_f32_16x16x32_bf16(a, wf, acc[f], 0, 0, 0);
                }
            }
            float ps[4] = {0,0,0,0}, pq[4] = {0,0,0,0};
            #pragma unroll
            for (int f = 0; f < 6; ++f) {
                int n = n0 + f*16 + cl;
                float bv = projb[n];
                #pragma unroll
                for (int r = 0; r < 4; ++r) {
                    float v = acc[f][r] + bv + x[(growbase + rb + r)*384 + n];
                    resv[f][r] = v;
                    ps[r] += v; pq[r] += v*v;
                }
            }
            #pragma unroll
            for (int off = 1; off < 16; off <<= 1)
                #pragma unroll
                for (int r = 0; r < 4; ++r) {
                    ps[r] += __shfl_xor(ps[r], off);
                    pq[r] += __shfl_xor(pq[r], off);
                }
            if (cl == 0)
                #pragma unroll
                for (int r = 0; r < 4; ++r) { redS[wid][rb+r] = ps[r]; redQ[wid][rb+r] = pq[r]; }
            __syncthreads();
            float mean[4], rstd[4];
            #pragma unroll
            for (int r = 0; r < 4; ++r) {
                int row = rb + r;
                float sv = redS[0][row]+redS[1][row]+redS[2][row]+redS[3][row];
                float qv = redQ[0][row]+redQ[1][row]+redQ[2][row]+redQ[3][row];
                mean[r] = sv * (1.f/384.f);
                float var = qv * (1.f/384.f) - mean[r]*mean[r];
                rstd[r] = rsqrtf(var + 1e-6f);
            }
            #pragma unroll
            for (int f = 0; f < 6; ++f) {
                int n = n0 + f*16 + cl;
                float g = ln2g[n], bb = ln2b[n];
                #pragma unroll
                for (int r = 0; r < 4; ++r)
                    xnS[(rb + r)*392 + n] = bf16s(fmaf((resv[f][r]-mean[r])*rstd[r], g, bb));
            }
            __syncthreads();
        }

        // ================= A3: fc1 + gelu =================
        for (int half = 0; half < 2; ++half) {
            int n0 = wid*384 + half*192;
            f32x4 acc[12];
            #pragma unroll
            for (int f = 0; f < 12; ++f) acc[f] = f32x4{0.f,0.f,0.f,0.f};
            const __hip_bfloat16* W0 = fc1w + (long)(n0 + cl)*384 + (hi<<3);
            for (int kt = 0; kt < 12; ++kt) {
                short8b a = *reinterpret_cast<const short8b*>(xnS + cl*392 + kt*32 + (hi<<3));
                #pragma unroll
                for (int f = 0; f < 12; ++f) {
                    short8b wf = *reinterpret_cast<const short8b*>(W0 + (long)f*16*384 + kt*32);
                    acc[f] = __builtin_amdgcn_mfma_f32_16x16x32_bf16(a, wf, acc[f], 0, 0, 0);
                }
            }
            #pragma unroll
            for (int f = 0; f < 12; ++f) {
                int n = n0 + f*16 + cl;
                float bv = fc1b[n];
                #pragma unroll
                for (int r = 0; r < 4; ++r)
                    hbS[(rb + r)*1544 + n] = bf16s(gelu_exact(acc[f][r] + bv));
            }
        }
        __syncthreads();

        // ================= A4: fc2 + residual (+LN1next) =================
        {
            int n0 = wid*96;
            f32x4 acc[6];
            #pragma unroll
            for (int f = 0; f < 6; ++f) acc[f] = f32x4{0.f,0.f,0.f,0.f};
            const __hip_bfloat16* W0 = fc2w + (long)(n0 + cl)*1536 + (hi<<3);
            for (int kt = 0; kt < 48; ++kt) {
                short8b a = *reinterpret_cast<const short8b*>(hbS + cl*1544 + kt*32 + (hi<<3));
                #pragma unroll
                for (int f = 0; f < 6; ++f) {
                    short8b wf = *reinterpret_cast<const short8b*>(W0 + (long)f*16*1536 + kt*32);
                    acc[f] = __builtin_amdgcn_mfma_f32_16x16x32_bf16(a, wf, acc[f], 0, 0, 0);
                }
            }
            float ps[4] = {0,0,0,0}, pq[4] = {0,0,0,0};
            float vv[6][4];
            #pragma unroll
            for (int f = 0; f < 6; ++f) {
                int n = n0 + f*16 + cl;
                float bv = fc2b[n];
                #pragma unroll
                for (int r = 0; r < 4; ++r) {
                    float v = acc[f][r] + bv + resv[f][r];
                    vv[f][r] = v;
                    x[(growbase + rb + r)*384 + n] = v;
                    ps[r] += v; pq[r] += v*v;
                }
            }
            if (MODE == 1) {
                #pragma unroll
                for (int off = 1; off < 16; off <<= 1)
                    #pragma unroll
                    for (int r = 0; r < 4; ++r) {
                        ps[r] += __shfl_xor(ps[r], off);
                        pq[r] += __shfl_xor(pq[r], off);
                    }
                if (cl == 0)
                    #pragma unroll
                    for (int r = 0; r < 4; ++r) { redS[wid][rb+r] = ps[r]; redQ[wid][rb+r] = pq[r]; }
                __syncthreads();
                float mean[4], rstd[4];
                #pragma unroll
                for (int r = 0; r < 4; ++r) {
                    int row = rb + r;
                    float sv = redS[0][row]+redS[1][row]+redS[2][row]+redS[3][row];
                    float qv = redQ[0][row]+redQ[1][row]+redQ[2][row]+redQ[3][row];
                    mean[r] = sv * (1.f/384.f);
                    float var = qv * (1.f/384.f) - mean[r]*mean[r];
                    rstd[r] = rsqrtf(var + 1e-6f);
                }
                #pragma unroll
                for (int f = 0; f < 6; ++f) {
                    int n = n0 + f*16 + cl;
                    float g = ln1g[n], bb = ln1b[n];
                    #pragma unroll
                    for (int r = 0; r < 4; ++r)
                        xnS[(rb + r)*392 + n] = bf16s(fmaf((vv[f][r]-mean[r])*rstd[r], g, bb));
                }
                __syncthreads();
            }
        }
    } else {
        // ============ MODE 0: LN1(layer0) from global x ============
        int n0 = wid*96;
        float ps[4] = {0,0,0,0}, pq[4] = {0,0,0,0};
        float vv[6][4];
        #pragma unroll
        for (int f = 0; f < 6; ++f) {
            int n = n0 + f*16 + cl;
            #pragma unroll
            for (int r = 0; r < 4; ++r) {
                float v = x[(growbase + rb + r)*384 + n];
                vv[f][r] = v;
                ps[r] += v; pq[r] += v*v;
            }
        }
        #pragma unroll
        for (int off = 1; off < 16; off <<= 1)
            #pragma unroll
            for (int r = 0; r < 4; ++r) {
                ps[r] += __shfl_xor(ps[r], off);
                pq[r] += __shfl_xor(pq[r], off);
            }
        if (cl == 0)
            #pragma unroll
            for (int r = 0; r < 4; ++r) { redS[wid][rb+r] = ps[r]; redQ[wid][rb+r] = pq[r]; }
        __syncthreads();
        float mean[4], rstd[4];
        #pragma unroll
        for (int r = 0; r < 4; ++r) {
            int row = rb + r;
            float sv = redS[0][row]+redS[1][row]+redS[2][row]+redS[3][row];
            float qv = redQ[0][row]+redQ[1][row]+redQ[2][row]+redQ[3][row];
            mean[r] = sv * (1.f/384.f);
            float var = qv * (1.f/384.f) - mean[r]*mean[r];
            rstd[r] = rsqrtf(var + 1e-6f);
        }
        #pragma unroll
        for (int f = 0; f < 6; ++f) {
            int n = n0 + f*16 + cl;
            float g = ln1g[n], bb = ln1b[n];
            #pragma unroll
            for (int r = 0; r < 4; ++r)
                xnS[(rb + r)*392 + n] = bf16s(fmaf((vv[f][r]-mean[r])*rstd[r], g, bb));
        }
        __syncthreads();
    }

    if (MODE != 2) {
        // ================= A5: QKV scatter (next layer) =================
        for (int j = 0; ; ++j) {
            int nt = wid + 4*j;
            if (nt >= 18) break;
            int n0 = nt*64;
            f32x4 acc[4];
            #pragma unroll
            for (int f = 0; f < 4; ++f) acc[f] = f32x4{0.f,0.f,0.f,0.f};
            const __hip_bfloat16* W0 = qkvw + (long)(n0 + cl)*384 + (hi<<3);
            for (int kt = 0; kt < 12; ++kt) {
                short8b a = *reinterpret_cast<const short8b*>(xnS + cl*392 + kt*32 + (hi<<3));
                #pragma unroll
                for (int f = 0; f < 4; ++f) {
                    short8b wf = *reinterpret_cast<const short8b*>(W0 + (long)f*16*384 + kt*32);
                    acc[f] = __builtin_amdgcn_mfma_f32_16x16x32_bf16(a, wf, acc[f], 0, 0, 0);
                }
            }
            #pragma unroll
            for (int f = 0; f < 4; ++f) {
                int n = n0 + f*16 + cl;
                float bv = qkvb[n];
                #pragma unroll
                for (int r = 0; r < 4; ++r) {
                    int tokr = tokr0 + rb + r;
                    float v = acc[f][r] + bv;
                    if (n < 384) {
                        int h = n >> 6, ch = n & 63;
                        qb[((long)(b*6 + h)*TOKP + tokr)*64 + ch] = __float2bfloat16(v * 0.125f);
                    } else if (n < 768) {
                        int nn = n - 384, h = nn >> 6, ch = nn & 63;
                        kb[((long)(b*6 + h)*TOKP + tokr)*64 + ch] = __float2bfloat16(v);
                    } else {
                        int nn = n - 768, h = nn >> 6, ch = nn & 63;
                        vT[((long)(b*6 + h)*64 + ch)*224 + tokr] = __float2bfloat16(v);
                    }
                }
            }
        }
    }
}

// ---------------------------------------------------------------------------
// Final LN (cls rows only) + head. Grid 10 blocks x 256; block j -> cols
// j*100 .. j*100+99 for both batches.
// ---------------------------------------------------------------------------
__global__ __launch_bounds__(256) void head_k(
    const float* __restrict__ x, const float* __restrict__ g,
    const float* __restrict__ bg, const float* __restrict__ hw,
    const float* __restrict__ hb, float* __restrict__ out)
{
    __shared__ float xn2[2][384];
    __shared__ float red[8];
    int t = threadIdx.x;
    int b = t >> 7, tt = t & 127;
    const float* xr = x + (long)b*TOKP*384;   // cls row of batch b
    float v0 = xr[tt], v1 = xr[tt+128], v2 = xr[tt+256];
    int wid = t >> 6, lane = t & 63;
    float sm = v0+v1+v2, sq = v0*v0+v1*v1+v2*v2;
    for (int off = 32; off; off >>= 1) { sm += __shfl_down(sm, off); sq += __shfl_down(sq, off); }
    if (lane == 0) { red[wid] = sm; red[4+wid] = sq; }
    __syncthreads();
    float s = red[b*2] + red[b*2+1], q = red[4+b*2] + red[4+b*2+1];
    float mean = s * (1.f/384.f);
    float var = q * (1.f/384.f) - mean*mean;
    float rstd = rsqrtf(var + 1e-6f);
    xn2[b][tt]     = fmaf((v0-mean)*rstd, g[tt],     bg[tt]);
    xn2[b][tt+128] = fmaf((v1-mean)*rstd, g[tt+128], bg[tt+128]);
    xn2[b][tt+256] = fmaf((v2-mean)*rstd, g[tt+256], bg[tt+256]);
    __syncthreads();
    if (t < 200) {
        int ob = t / 100, n = blockIdx.x*100 + t % 100;
        const float4* xp = reinterpret_cast<const float4*>(xn2[ob]);
        const float4* wp = reinterpret_cast<const float4*>(hw + (long)n*384);
        float a = hb[n];
        for (int d = 0; d < 96; ++d) {
            float4 xv = xp[d], wv = wp[d];
            a = fmaf(xv.x,wv.x, fmaf(xv.y,wv.y, fmaf(xv.z,wv.z, fmaf(xv.w,wv.w, a))));
        }
        out[ob*1000 + n] = a;
    }
}

// ---------------------------------------------------------------------------
extern "C" void kernel_launch(void* const* d_in, const int* in_sizes, int n_in,
                              void* d_out, int out_size, void* d_ws, size_t ws_size,
                              hipStream_t stream)
{
    const float* img      = (const float*)d_in[0];
    const float* fp_w     = (const float*)d_in[2];
    const float* fp_b     = (const float*)d_in[3];
    const float* ap_in_w  = (const float*)d_in[4];
    const float* ap_in_b  = (const float*)d_in[5];
    const float* ap_out_w = (const float*)d_in[6];
    const float* ap_out_b = (const float*)d_in[7];
    const float* cls_tok  = (const float*)d_in[8];
    const float* pos_emb  = (const float*)d_in[9];
    const float* ln1_g    = (const float*)d_in[10];
    const float* ln1_b    = (const float*)d_in[11];
    const float* qkv_w    = (const float*)d_in[12];
    const float* qkv_b    = (const float*)d_in[13];
    const float* proj_w   = (const float*)d_in[14];
    const float* proj_b   = (const float*)d_in[15];
    const float* ln2_g    = (const float*)d_in[16];
    const float* ln2_b    = (const float*)d_in[17];
    const float* fc1_w    = (const float*)d_in[18];
    const float* fc1_b    = (const float*)d_in[19];
    const float* fc2_w    = (const float*)d_in[20];
    const float* fc2_b    = (const float*)d_in[21];
    const float* norm_g   = (const float*)d_in[22];
    const float* norm_b   = (const float*)d_in[23];
    const float* head_w   = (const float*)d_in[24];
    const float* head_b   = (const float*)d_in[25];
    (void)in_sizes; (void)n_in; (void)out_size; (void)ws_size;
    float* out = (float*)d_out;

    float* ws = (float*)d_ws;
    size_t off = 0;
    auto alloc = [&](size_t nfl) { float* p = ws + off; off += (nfl + 63) & ~(size_t)63; return p; };
    float* W2     = alloc(1152*3);
    float* b2     = alloc(1152);
    float* hGm    = alloc(64);
    float* tok    = alloc(392L*384);
    float* x      = alloc(2L*TOKP*384);
    __hip_bfloat16* pooledb = (__hip_bfloat16*)alloc(392L*384/2);
    __hip_bfloat16* qb      = (__hip_bfloat16*)alloc(12L*TOKP*64/2);
    __hip_bfloat16* kb      = (__hip_bfloat16*)alloc(12L*TOKP*64/2);
    __hip_bfloat16* vT      = (__hip_bfloat16*)alloc(12L*64*224/2);
    __hip_bfloat16* qkvwb   = (__hip_bfloat16*)alloc(12L*1152*384/2);
    __hip_bfloat16* projwb  = (__hip_bfloat16*)alloc(12L*384*384/2);
    __hip_bfloat16* fc1wb   = (__hip_bfloat16*)alloc(12L*1536*384/2);
    __hip_bfloat16* fc2wb   = (__hip_bfloat16*)alloc(12L*384*1536/2);
    __hip_bfloat16* apoutwb = (__hip_bfloat16*)alloc(384L*384/2);

    // ---- weight conversion + pad init ----
    {
        int n1 = 12*1152*384, n2 = 12*384*384, n3 = 12*1536*384, n4 = 384*384;
        cvt_bf16_k<<<(n1/4 + 255)/256, 256, 0, stream>>>(qkv_w,  qkvwb,  n1);
        cvt_bf16_k<<<(n2/4 + 255)/256, 256, 0, stream>>>(proj_w, projwb, n2);
        cvt_bf16_k<<<(n3/4 + 255)/256, 256, 0, stream>>>(fc1_w,  fc1wb,  n3);
        cvt_bf16_k<<<(n3/4 + 255)/256, 256, 0, stream>>>(fc2_w,  fc2wb,  n3);
        cvt_bf16_k<<<(n4/4 + 255)/256, 256, 0, stream>>>(ap_out_w, apoutwb, n4);
        init_k<<<(12*64*16 + 255)/256, 256, 0, stream>>>(vT);
    }

    // ---- tokenizer ----
    prep_w2_k<<<5, 256, 0, stream>>>(ap_in_w, ap_in_b, fp_w, fp_b, W2, b2);
    prep_head_k<<<4, 64, 0, stream>>>(W2, b2, hGm);
    tok_attn_k<<<dim3(196,4,2), 256, 0, stream>>>(img, hGm, W2, b2, pooledb);
    gemm_mfma_k<<<dim3(25,6), 64, 0, stream>>>(
        pooledb, apoutwb, ap_out_b, tok, 392, 384, 384, 384, 384, 384);
    build_x0_k<<<(2*TOKP*384 + 255)/256, 256, 0, stream>>>(tok, cls_tok, pos_emb, x);

    // ---- trunk: 13 layer dispatches ----
    layer_k<0><<<26, 256, 0, stream>>>(
        x, qb, kb, vT,
        nullptr, nullptr, nullptr, nullptr, nullptr, nullptr, nullptr, nullptr,
        ln1_g, ln1_b, qkvwb, qkv_b);
    for (int i = 0; i < 11; ++i) {
        layer_k<1><<<26, 256, 0, stream>>>(
            x, qb, kb, vT,
            projwb + (long)i*384*384, proj_b + i*384,
            ln2_g + i*384, ln2_b + i*384,
            fc1wb + (long)i*1536*384, fc1_b + i*1536,
            fc2wb + (long)i*384*1536, fc2_b + i*384,
            ln1_g + (i+1)*384, ln1_b + (i+1)*384,
            qkvwb + (long)(i+1)*1152*384, qkv_b + (i+1)*1152);
    }
    layer_k<2><<<26, 256, 0, stream>>>(
        x, qb, kb, vT,
        projwb + 11L*384*384, proj_b + 11*384,
        ln2_g + 11*384, ln2_b + 11*384,
        fc1wb + 11L*1536*384, fc1_b + 11*1536,
        fc2wb + 11L*384*1536, fc2_b + 11*384,
        nullptr, nullptr, nullptr, nullptr);

    // ---- head ----
    head_k<<<10, 256, 0, stream>>>(x, norm_g, norm_b, head_w, head_b, out);
}

// Round 8
// 908.841 us; speedup vs baseline: 4.3747x; 2.0804x over previous
//
#include <hip/hip_runtime.h>
#include <hip/hip_bf16.h>
#include <math.h>

// ---------------------------------------------------------------------------
// Model dims: B=2, Cn=3, HI=WI=224, S=196, P=256, D=384, H_TOK=4
// DEPTH=12, H_VIT=6 (dh=64), HID=1536, NCLS=1000
// x layout: [394][384] f32 (rows 0,197 = cls; 1..196,198..393 = tokens)
// ---------------------------------------------------------------------------

typedef __attribute__((ext_vector_type(8))) short short8b;
typedef __attribute__((ext_vector_type(4))) float f32x4;

static __device__ __forceinline__ float gelu_exact(float v) {
    return 0.5f * v * (1.0f + erff(v * 0.70710678118654752440f));
}
static __device__ __forceinline__ short bf16s(float f) {
    __hip_bfloat16 h = __float2bfloat16(f);
    return *reinterpret_cast<short*>(&h);
}

// ---------------------------------------------------------------------------
// One-shot setup: convert all 5 weight groups f32->bf16 + zero vT key pad.
// Segment sizes (elements, all %4==0).
// ---------------------------------------------------------------------------
__global__ __launch_bounds__(256) void cvt_all_k(
    const float* __restrict__ qw, const float* __restrict__ pw,
    const float* __restrict__ f1w, const float* __restrict__ f2w,
    const float* __restrict__ aow,
    __hip_bfloat16* __restrict__ qd, __hip_bfloat16* __restrict__ pd,
    __hip_bfloat16* __restrict__ f1d, __hip_bfloat16* __restrict__ f2d,
    __hip_bfloat16* __restrict__ aod, __hip_bfloat16* __restrict__ vT)
{
    const long N1 = 5308416, N2 = 1769472, N3 = 7077888, N4 = 147456;
    long t = (long)blockIdx.x*256 + threadIdx.x;
    long idx = t * 4;
    const float* src = nullptr; __hip_bfloat16* dst = nullptr; long off = 0;
    if (idx < N1)                { src=qw;  dst=qd;  off=idx; }
    else if (idx < N1+N2)        { src=pw;  dst=pd;  off=idx-N1; }
    else if (idx < N1+N2+N3)     { src=f1w; dst=f1d; off=idx-N1-N2; }
    else if (idx < N1+N2+2*N3)   { src=f2w; dst=f2d; off=idx-N1-N2-N3; }
    else if (idx < N1+N2+2*N3+N4){ src=aow; dst=aod; off=idx-N1-N2-2*N3; }
    if (src) {
        float4 v = *reinterpret_cast<const float4*>(src + off);
        dst[off+0] = __float2bfloat16(v.x);
        dst[off+1] = __float2bfloat16(v.y);
        dst[off+2] = __float2bfloat16(v.z);
        dst[off+3] = __float2bfloat16(v.w);
    }
    if (t < 12*64*27) {
        int c = (int)(t % 27), r = (int)(t / 27);
        vT[(long)r*224 + 197 + c] = __float2bfloat16(0.f);
    }
}

// ---------------------------------------------------------------------------
// prep: W2[1152][3] = ap_in_w @ fp_w ; b2 = ap_in_b + ap_in_w @ fp_b.
// Also: x cls rows (0 and 197) = cls + pos[0].
// ---------------------------------------------------------------------------
__global__ __launch_bounds__(256) void prep_w2_k(
    const float* __restrict__ ap_in_w, const float* __restrict__ ap_in_b,
    const float* __restrict__ fp_w, const float* __restrict__ fp_b,
    const float* __restrict__ cls, const float* __restrict__ pos,
    float* __restrict__ W2, float* __restrict__ b2, float* __restrict__ x)
{
    int o = blockIdx.x * 256 + threadIdx.x;
    if (o < 384) {
        float v = cls[o] + pos[o];
        x[o] = v;
        x[197*384 + o] = v;
    }
    if (o >= 1152) return;
    const float* ar = ap_in_w + (long)o * 384;
    float a0 = 0.f, a1 = 0.f, a2 = 0.f, ab = ap_in_b[o];
    for (int d = 0; d < 384; ++d) {
        float aw = ar[d];
        a0 = fmaf(aw, fp_w[d*3+0], a0);
        a1 = fmaf(aw, fp_w[d*3+1], a1);
        a2 = fmaf(aw, fp_w[d*3+2], a2);
        ab = fmaf(aw, fp_b[d], ab);
    }
    W2[o*3+0] = a0; W2[o*3+1] = a1; W2[o*3+2] = a2; b2[o] = ab;
}

// ---------------------------------------------------------------------------
// prep per-head bilinear form (scaled by 1/sqrt(96))
// ---------------------------------------------------------------------------
__global__ __launch_bounds__(64) void prep_head_k(
    const float* __restrict__ W2, const float* __restrict__ b2,
    float* __restrict__ hGm)
{
    int h = blockIdx.x;
    int lane = threadIdx.x;
    float G00=0,G01=0,G02=0,G10=0,G11=0,G12=0,G20=0,G21=0,G22=0;
    float u0=0,u1=0,u2=0,w0=0,w1=0,w2=0,c0=0;
    for (int d = lane; d < 96; d += 64) {
        int oq = h*96 + d, ok = 384 + h*96 + d;
        float q0=W2[oq*3],q1=W2[oq*3+1],q2=W2[oq*3+2];
        float k0=W2[ok*3],k1=W2[ok*3+1],k2=W2[ok*3+2];
        float bq=b2[oq], bk=b2[ok];
        G00=fmaf(q0,k0,G00); G01=fmaf(q0,k1,G01); G02=fmaf(q0,k2,G02);
        G10=fmaf(q1,k0,G10); G11=fmaf(q1,k1,G11); G12=fmaf(q1,k2,G12);
        G20=fmaf(q2,k0,G20); G21=fmaf(q2,k1,G21); G22=fmaf(q2,k2,G22);
        u0=fmaf(q0,bk,u0); u1=fmaf(q1,bk,u1); u2=fmaf(q2,bk,u2);
        w0=fmaf(k0,bq,w0); w1=fmaf(k1,bq,w1); w2=fmaf(k2,bq,w2);
        c0=fmaf(bq,bk,c0);
    }
    float vals[16] = {G00,G01,G02,u0, G10,G11,G12,u1, G20,G21,G22,u2, w0,w1,w2,c0};
    const float sc = 0.10206207261596577f; // 1/sqrt(96)
    #pragma unroll
    for (int q = 0; q < 16; ++q) {
        float v = vals[q];
        for (int off = 32; off; off >>= 1) v += __shfl_down(v, off);
        if (lane == 0) hGm[h*16 + q] = v * sc;
    }
}

// ---------------------------------------------------------------------------
// Tokenizer attention, 2-pass (validated R6/R7). One block per (s,h,b).
// ---------------------------------------------------------------------------
__global__ __launch_bounds__(256) void tok_attn_k(
    const float* __restrict__ img, const float* __restrict__ hGm,
    const float* __restrict__ W2, const float* __restrict__ b2,
    __hip_bfloat16* __restrict__ pooledb)
{
    int s = blockIdx.x, h = blockIdx.y, b = blockIdx.z;
    int t = threadIdx.x;
    __shared__ float4 pxm[256];
    __shared__ float4 ylds[256];
    __shared__ float  Ash[256];
    __shared__ float  tsum[3];

    int gy = s / 14, gx = s - gy*14;
    int row = gy*16 + (t >> 4), col = gx*16 + (t & 15);
    long base = ((long)b*3*224 + row)*224 + col;
    float p0 = img[base];
    float p1 = img[base + 224*224];
    float p2 = img[base + 2*224*224];

    const float4* M4 = reinterpret_cast<const float4*>(hGm) + h*4;
    float4 r0 = M4[0], r1 = M4[1], r2 = M4[2], r3 = M4[3];
    float y0 = fmaf(p0,r0.x, fmaf(p1,r0.y, fmaf(p2,r0.z, r0.w)));
    float y1 = fmaf(p0,r1.x, fmaf(p1,r1.y, fmaf(p2,r1.z, r1.w)));
    float y2 = fmaf(p0,r2.x, fmaf(p1,r2.y, fmaf(p2,r2.z, r2.w)));
    float y3 = fmaf(p0,r3.x, fmaf(p1,r3.y, fmaf(p2,r3.z, r3.w)));
    ylds[t] = make_float4(y0,y1,y2,y3);
    pxm[t]  = make_float4(p0,p1,p2,0.f);
    __syncthreads();

    float li = 0.f;
    #pragma unroll 4
    for (int j = 0; j < 256; ++j) {
        float4 Y = ylds[j];
        float scr = fmaf(p0,Y.x, fmaf(p1,Y.y, fmaf(p2,Y.z, Y.w)));
        li += __expf(scr);
    }
    pxm[t].w = -__logf(li);
    __syncthreads();

    float Aj = 0.f;
    #pragma unroll 4
    for (int i = 0; i < 256; ++i) {
        float4 q = pxm[i];
        float scr = fmaf(q.x,y0, fmaf(q.y,y1, fmaf(q.z,y2, y3))) + q.w;
        Aj += __expf(scr);
    }
    Ash[t] = Aj;
    __syncthreads();

    int w = t >> 6, lane = t & 63;
    if (w < 3) {
        float prt = 0.f;
        for (int j = lane; j < 256; j += 64) {
            const float* pj = reinterpret_cast<const float*>(&pxm[j]);
            prt = fmaf(Ash[j], pj[w], prt);
        }
        for (int off = 32; off; off >>= 1) prt += __shfl_down(prt, off);
        if (lane == 0) tsum[w] = prt;
    }
    __syncthreads();

    if (t < 96) {
        int o = 768 + h*96 + t;
        float v = (W2[o*3]*tsum[0] + W2[o*3+1]*tsum[1] + W2[o*3+2]*tsum[2]) * (1.f/256.f)
                  + b2[o];
        pooledb[((long)(b*196 + s))*384 + h*96 + t] = __float2bfloat16(v);
    }
}

// ---------------------------------------------------------------------------
// Tokenizer out-proj -> x directly, pos-embed fused.
// pooled[392][384] @ apout^T + apout_b ; row m=b*196+s -> x row m+b+1,
// plus pos[(s+1)*384+n].
// ---------------------------------------------------------------------------
__global__ __launch_bounds__(64) void outproj_x_k(
    const __hip_bfloat16* __restrict__ A, const __hip_bfloat16* __restrict__ W,
    const float* __restrict__ bias, const float* __restrict__ pos,
    float* __restrict__ x)
{
    int l = threadIdx.x;
    int m0 = blockIdx.x * 16, n0 = blockIdx.y * 64;
    int arow = m0 + (l & 15); if (arow >= 392) arow = 391;
    const __hip_bfloat16* Ap = A + (long)arow * 384 + ((l >> 4) << 3);
    const __hip_bfloat16* W0 = W + (long)(n0 + (l & 15)) * 384 + ((l >> 4) << 3);

    f32x4 acc[4];
    #pragma unroll
    for (int f = 0; f < 4; ++f) acc[f] = f32x4{0.f,0.f,0.f,0.f};
    #pragma unroll 4
    for (int kt = 0; kt < 12; ++kt) {
        int k = kt << 5;
        short8b a  = *reinterpret_cast<const short8b*>(Ap + k);
        short8b b0 = *reinterpret_cast<const short8b*>(W0 + k);
        short8b b1 = *reinterpret_cast<const short8b*>(W0 + 16L*384 + k);
        short8b b2 = *reinterpret_cast<const short8b*>(W0 + 32L*384 + k);
        short8b b3 = *reinterpret_cast<const short8b*>(W0 + 48L*384 + k);
        acc[0] = __builtin_amdgcn_mfma_f32_16x16x32_bf16(a, b0, acc[0], 0, 0, 0);
        acc[1] = __builtin_amdgcn_mfma_f32_16x16x32_bf16(a, b1, acc[1], 0, 0, 0);
        acc[2] = __builtin_amdgcn_mfma_f32_16x16x32_bf16(a, b2, acc[2], 0, 0, 0);
        acc[3] = __builtin_amdgcn_mfma_f32_16x16x32_bf16(a, b3, acc[3], 0, 0, 0);
    }

    int cl = l & 15;
    int rbase = m0 + ((l >> 4) << 2);
    #pragma unroll
    for (int f = 0; f < 4; ++f) {
        int n = n0 + f*16 + cl;
        float bv = bias[n];
        #pragma unroll
        for (int r = 0; r < 4; ++r) {
            int m = rbase + r;
            if (m >= 392) continue;
            int b = m / 196;
            int srow = m - 196*b + 1;
            x[(long)(m + b + 1)*384 + n] = acc[f][r] + bv + pos[(long)srow*384 + n];
        }
    }
}

// ---------------------------------------------------------------------------
// MFMA bf16 GEMM, 1 wave/block, 16x64 tile (proj, fc2). Validated R2/R3.
// ---------------------------------------------------------------------------
template<bool GEL, bool RES, bool OBF>
__global__ __launch_bounds__(64) void gemm_mfma_k(
    const __hip_bfloat16* __restrict__ A, const __hip_bfloat16* __restrict__ W,
    const float* __restrict__ bias, const float* __restrict__ resid,
    void* __restrict__ Cv, int M, int N, int K, int lda, int ldw, int ldc,
    int kpart, long sC)
{
    int l = threadIdx.x;
    int m0 = blockIdx.x * 16, n0 = blockIdx.y * 64;
    int z = blockIdx.z;
    int ks = z * kpart;
    int klen = K - ks; if (klen > kpart) klen = kpart;

    int arow = m0 + (l & 15); if (arow >= M) arow = M - 1;
    const __hip_bfloat16* Ap = A + (long)arow * lda + ks + ((l >> 4) << 3);
    const __hip_bfloat16* W0 = W + (long)(n0 + (l & 15)) * ldw + ks + ((l >> 4) << 3);
    long wst = (long)ldw * 16;

    f32x4 acc[4];
    #pragma unroll
    for (int f = 0; f < 4; ++f) acc[f] = f32x4{0.f,0.f,0.f,0.f};

    int niter = klen >> 5;
    #pragma unroll 4
    for (int kt = 0; kt < niter; ++kt) {
        int k = kt << 5;
        short8b a  = *reinterpret_cast<const short8b*>(Ap + k);
        short8b b0 = *reinterpret_cast<const short8b*>(W0 + k);
        short8b b1 = *reinterpret_cast<const short8b*>(W0 + wst + k);
        short8b b2 = *reinterpret_cast<const short8b*>(W0 + 2*wst + k);
        short8b b3 = *reinterpret_cast<const short8b*>(W0 + 3*wst + k);
        acc[0] = __builtin_amdgcn_mfma_f32_16x16x32_bf16(a, b0, acc[0], 0, 0, 0);
        acc[1] = __builtin_amdgcn_mfma_f32_16x16x32_bf16(a, b1, acc[1], 0, 0, 0);
        acc[2] = __builtin_amdgcn_mfma_f32_16x16x32_bf16(a, b2, acc[2], 0, 0, 0);
        acc[3] = __builtin_amdgcn_mfma_f32_16x16x32_bf16(a, b3, acc[3], 0, 0, 0);
    }

    int cl = l & 15;
    int rbase = m0 + ((l >> 4) << 2);
    float* Cf = (float*)Cv + z * sC;
    __hip_bfloat16* Cb = (__hip_bfloat16*)Cv;
    #pragma unroll
    for (int f = 0; f < 4; ++f) {
        int n = n0 + f*16 + cl;
        float bv = bias ? bias[n] : 0.f;
        #pragma unroll
        for (int r = 0; r < 4; ++r) {
            int m = rbase + r;
            if (m >= M) continue;
            float v = acc[f][r] + bv;
            if (GEL) v = gelu_exact(v);
            if (RES) v += resid[(long)m*ldc + n];
            if (OBF) Cb[(long)m*ldc + n] = __float2bfloat16(v);
            else     Cf[(long)m*ldc + n] = v;
        }
    }
}

// ---------------------------------------------------------------------------
// Fused LayerNorm + MFMA GEMM (K=384). Validated R3.
// EPI=1: qkv scatter to qb/kb (x0.125 on q) /vT.  EPI=2: gelu -> bf16 C.
// ---------------------------------------------------------------------------
template<int EPI>
__global__ __launch_bounds__(64) void ln_gemm_k(
    const float* __restrict__ x, const float* __restrict__ g,
    const float* __restrict__ b, const __hip_bfloat16* __restrict__ W,
    const float* __restrict__ bias,
    __hip_bfloat16* __restrict__ o0, __hip_bfloat16* __restrict__ o1,
    __hip_bfloat16* __restrict__ o2, int M, int N)
{
    int l = threadIdx.x;
    int m0 = blockIdx.x * 16, n0 = blockIdx.y * 64;
    int cl = l & 15, hi = l >> 4;
    int row = m0 + cl; if (row >= M) row = M - 1;
    const float* xp = x + (long)row*384 + (hi << 3);

    float sum = 0.f, sq = 0.f;
    #pragma unroll
    for (int t = 0; t < 12; ++t) {
        float4 v0 = *reinterpret_cast<const float4*>(xp + t*32);
        float4 v1 = *reinterpret_cast<const float4*>(xp + t*32 + 4);
        sum += v0.x+v0.y+v0.z+v0.w + v1.x+v1.y+v1.z+v1.w;
        sq  += v0.x*v0.x+v0.y*v0.y+v0.z*v0.z+v0.w*v0.w
             + v1.x*v1.x+v1.y*v1.y+v1.z*v1.z+v1.w*v1.w;
    }
    sum += __shfl_xor(sum, 16); sum += __shfl_xor(sum, 32);
    sq  += __shfl_xor(sq, 16);  sq  += __shfl_xor(sq, 32);
    float mean = sum * (1.f/384.f);
    float var  = sq * (1.f/384.f) - mean*mean;
    float rstd = rsqrtf(var + 1e-6f);

    const __hip_bfloat16* Wp = W + (long)(n0 + cl)*384 + (hi << 3);
    f32x4 acc[4];
    #pragma unroll
    for (int f = 0; f < 4; ++f) acc[f] = f32x4{0.f,0.f,0.f,0.f};

    #pragma unroll 2
    for (int t = 0; t < 12; ++t) {
        int k = t*32 + (hi << 3);
        float4 v0 = *reinterpret_cast<const float4*>(xp + t*32);
        float4 v1 = *reinterpret_cast<const float4*>(xp + t*32 + 4);
        float4 g0 = *reinterpret_cast<const float4*>(g + k);
        float4 g1 = *reinterpret_cast<const float4*>(g + k + 4);
        float4 bb0 = *reinterpret_cast<const float4*>(b + k);
        float4 bb1 = *reinterpret_cast<const float4*>(b + k + 4);
        short8b a;
        a[0] = bf16s(fmaf((v0.x-mean)*rstd, g0.x, bb0.x));
        a[1] = bf16s(fmaf((v0.y-mean)*rstd, g0.y, bb0.y));
        a[2] = bf16s(fmaf((v0.z-mean)*rstd, g0.z, bb0.z));
        a[3] = bf16s(fmaf((v0.w-mean)*rstd, g0.w, bb0.w));
        a[4] = bf16s(fmaf((v1.x-mean)*rstd, g1.x, bb1.x));
        a[5] = bf16s(fmaf((v1.y-mean)*rstd, g1.y, bb1.y));
        a[6] = bf16s(fmaf((v1.z-mean)*rstd, g1.z, bb1.z));
        a[7] = bf16s(fmaf((v1.w-mean)*rstd, g1.w, bb1.w));
        short8b w0 = *reinterpret_cast<const short8b*>(Wp + t*32);
        short8b w1 = *reinterpret_cast<const short8b*>(Wp + 16L*384 + t*32);
        short8b w2 = *reinterpret_cast<const short8b*>(Wp + 32L*384 + t*32);
        short8b w3 = *reinterpret_cast<const short8b*>(Wp + 48L*384 + t*32);
        acc[0] = __builtin_amdgcn_mfma_f32_16x16x32_bf16(a, w0, acc[0], 0, 0, 0);
        acc[1] = __builtin_amdgcn_mfma_f32_16x16x32_bf16(a, w1, acc[1], 0, 0, 0);
        acc[2] = __builtin_amdgcn_mfma_f32_16x16x32_bf16(a, w2, acc[2], 0, 0, 0);
        acc[3] = __builtin_amdgcn_mfma_f32_16x16x32_bf16(a, w3, acc[3], 0, 0, 0);
    }

    int rb = hi << 2;
    #pragma unroll
    for (int f = 0; f < 4; ++f) {
        int n = n0 + f*16 + cl;
        float bv = bias[n];
        #pragma unroll
        for (int r = 0; r < 4; ++r) {
            int m = m0 + rb + r;
            if (m >= M) continue;
            float v = acc[f][r] + bv;
            if (EPI == 1) {
                int bb = (m >= 197) ? 1 : 0;
                int tokr = m - bb*197;
                if (n < 384) {
                    int h = n >> 6, ch = n & 63;
                    o0[((long)(bb*6 + h)*208 + tokr)*64 + ch] = __float2bfloat16(v * 0.125f);
                } else if (n < 768) {
                    int nn = n - 384, h = nn >> 6, ch = nn & 63;
                    o1[((long)(bb*6 + h)*208 + tokr)*64 + ch] = __float2bfloat16(v);
                } else {
                    int nn = n - 768, h = nn >> 6, ch = nn & 63;
                    o2[((long)(bb*6 + h)*64 + ch)*224 + tokr] = __float2bfloat16(v);
                }
            } else { // EPI == 2
                o0[(long)m*N + n] = __float2bfloat16(gelu_exact(v));
            }
        }
    }
}

// ---------------------------------------------------------------------------
// Fused flash attention (validated R3). grid (13 qt, 12 bh), 1 wave.
// ---------------------------------------------------------------------------
__global__ __launch_bounds__(64) void attn_flash_k(
    const __hip_bfloat16* __restrict__ qb, const __hip_bfloat16* __restrict__ kb,
    const __hip_bfloat16* __restrict__ vT, __hip_bfloat16* __restrict__ attnb)
{
    __shared__ __align__(16) short lp[16*232];
    int l = threadIdx.x;
    int qt = blockIdx.x, bh = blockIdx.y;
    int q0 = qt * 16;
    int cl = l & 15, hi = l >> 4;

    if (l < 32) {
        int row = l >> 1, hf = l & 1;
        *reinterpret_cast<int4*>(lp + row*232 + 208 + hf*8) = int4{0,0,0,0};
    }

    const __hip_bfloat16* Qp = qb + ((long)bh*208 + q0 + cl)*64 + (hi << 3);
    const __hip_bfloat16* Kp = kb + ((long)bh*208 + cl)*64 + (hi << 3);
    f32x4 s[13];
    #pragma unroll
    for (int f = 0; f < 13; ++f) s[f] = f32x4{0.f,0.f,0.f,0.f};
    #pragma unroll
    for (int kt = 0; kt < 2; ++kt) {
        short8b a = *reinterpret_cast<const short8b*>(Qp + kt*32);
        #pragma unroll
        for (int f = 0; f < 13; ++f) {
            short8b kk = *reinterpret_cast<const short8b*>(Kp + (long)f*16*64 + kt*32);
            s[f] = __builtin_amdgcn_mfma_f32_16x16x32_bf16(a, kk, s[f], 0, 0, 0);
        }
    }
    if (cl >= 5) s[12] = f32x4{-1e30f,-1e30f,-1e30f,-1e30f};

    #pragma unroll
    for (int r = 0; r < 4; ++r) {
        float m = s[0][r];
        #pragma unroll
        for (int f = 1; f < 13; ++f) m = fmaxf(m, s[f][r]);
        m = fmaxf(m, __shfl_xor(m, 1));
        m = fmaxf(m, __shfl_xor(m, 2));
        m = fmaxf(m, __shfl_xor(m, 4));
        m = fmaxf(m, __shfl_xor(m, 8));
        float e[13]; float ssum = 0.f;
        #pragma unroll
        for (int f = 0; f < 13; ++f) { e[f] = __expf(s[f][r] - m); ssum += e[f]; }
        ssum += __shfl_xor(ssum, 1);
        ssum += __shfl_xor(ssum, 2);
        ssum += __shfl_xor(ssum, 4);
        ssum += __shfl_xor(ssum, 8);
        float ri = 1.f / ssum;
        int prow = (hi << 2) + r;
        #pragma unroll
        for (int f = 0; f < 13; ++f)
            lp[prow*232 + f*16 + cl] = bf16s(e[f] * ri);
    }
    __syncthreads();

    f32x4 o[4];
    #pragma unroll
    for (int f = 0; f < 4; ++f) o[f] = f32x4{0.f,0.f,0.f,0.f};
    const __hip_bfloat16* Vp = vT + ((long)bh*64 + cl)*224 + (hi << 3);
    #pragma unroll
    for (int kt = 0; kt < 7; ++kt) {
        short8b pa = *reinterpret_cast<const short8b*>(&lp[cl*232 + (hi << 3) + kt*32]);
        #pragma unroll
        for (int f2 = 0; f2 < 4; ++f2) {
            short8b vb = *reinterpret_cast<const short8b*>(Vp + (long)f2*16*224 + kt*32);
            o[f2] = __builtin_amdgcn_mfma_f32_16x16x32_bf16(pa, vb, o[f2], 0, 0, 0);
        }
    }

    int b = bh / 6, h = bh - b*6;
    #pragma unroll
    for (int f2 = 0; f2 < 4; ++f2) {
        int ch = h*64 + f2*16 + cl;
        #pragma unroll
        for (int r = 0; r < 4; ++r) {
            int qr = q0 + (hi << 2) + r;
            if (qr < 197)
                attnb[((long)(b*197 + qr))*384 + ch] = __float2bfloat16(o[f2][r]);
        }
    }
}

// ---------------------------------------------------------------------------
// Final LN (cls rows only) + head (validated R7; x row stride 197/batch).
// Grid 10 x 256; block j covers output cols j*100..j*100+99, both batches.
// ---------------------------------------------------------------------------
__global__ __launch_bounds__(256) void head_k(
    const float* __restrict__ x, const float* __restrict__ g,
    const float* __restrict__ bg, const float* __restrict__ hw,
    const float* __restrict__ hb, float* __restrict__ out)
{
    __shared__ float xn2[2][384];
    __shared__ float red[8];
    int t = threadIdx.x;
    int b = t >> 7, tt = t & 127;
    const float* xr = x + (long)(b*197)*384;   // cls row of batch b
    float v0 = xr[tt], v1 = xr[tt+128], v2 = xr[tt+256];
    int wid = t >> 6, lane = t & 63;
    float sm = v0+v1+v2, sq = v0*v0+v1*v1+v2*v2;
    for (int off = 32; off; off >>= 1) { sm += __shfl_down(sm, off); sq += __shfl_down(sq, off); }
    if (lane == 0) { red[wid] = sm; red[4+wid] = sq; }
    __syncthreads();
    float s = red[b*2] + red[b*2+1], q = red[4+b*2] + red[4+b*2+1];
    float mean = s * (1.f/384.f);
    float var = q * (1.f/384.f) - mean*mean;
    float rstd = rsqrtf(var + 1e-6f);
    xn2[b][tt]     = fmaf((v0-mean)*rstd, g[tt],     bg[tt]);
    xn2[b][tt+128] = fmaf((v1-mean)*rstd, g[tt+128], bg[tt+128]);
    xn2[b][tt+256] = fmaf((v2-mean)*rstd, g[tt+256], bg[tt+256]);
    __syncthreads();
    if (t < 200) {
        int ob = t / 100, n = blockIdx.x*100 + t % 100;
        const float4* xp = reinterpret_cast<const float4*>(xn2[ob]);
        const float4* wp = reinterpret_cast<const float4*>(hw + (long)n*384);
        float a = hb[n];
        for (int d = 0; d < 96; ++d) {
            float4 xv = xp[d], wv = wp[d];
            a = fmaf(xv.x,wv.x, fmaf(xv.y,wv.y, fmaf(xv.z,wv.z, fmaf(xv.w,wv.w, a))));
        }
        out[ob*1000 + n] = a;
    }
}

// ---------------------------------------------------------------------------
extern "C" void kernel_launch(void* const* d_in, const int* in_sizes, int n_in,
                              void* d_out, int out_size, void* d_ws, size_t ws_size,
                              hipStream_t stream)
{
    const float* img      = (const float*)d_in[0];
    const float* fp_w     = (const float*)d_in[2];
    const float* fp_b     = (const float*)d_in[3];
    const float* ap_in_w  = (const float*)d_in[4];
    const float* ap_in_b  = (const float*)d_in[5];
    const float* ap_out_w = (const float*)d_in[6];
    const float* ap_out_b = (const float*)d_in[7];
    const float* cls_tok  = (const float*)d_in[8];
    const float* pos_emb  = (const float*)d_in[9];
    const float* ln1_g    = (const float*)d_in[10];
    const float* ln1_b    = (const float*)d_in[11];
    const float* qkv_w    = (const float*)d_in[12];
    const float* qkv_b    = (const float*)d_in[13];
    const float* proj_w   = (const float*)d_in[14];
    const float* proj_b   = (const float*)d_in[15];
    const float* ln2_g    = (const float*)d_in[16];
    const float* ln2_b    = (const float*)d_in[17];
    const float* fc1_w    = (const float*)d_in[18];
    const float* fc1_b    = (const float*)d_in[19];
    const float* fc2_w    = (const float*)d_in[20];
    const float* fc2_b    = (const float*)d_in[21];
    const float* norm_g   = (const float*)d_in[22];
    const float* norm_b   = (const float*)d_in[23];
    const float* head_w   = (const float*)d_in[24];
    const float* head_b   = (const float*)d_in[25];
    (void)in_sizes; (void)n_in; (void)out_size; (void)ws_size;
    float* out = (float*)d_out;

    float* ws = (float*)d_ws;
    size_t off = 0;
    auto alloc = [&](size_t nfl) { float* p = ws + off; off += (nfl + 63) & ~(size_t)63; return p; };
    float* W2     = alloc(1152*3);
    float* b2     = alloc(1152);
    float* hGm    = alloc(64);
    float* x      = alloc(394L*384);
    __hip_bfloat16* pooledb = (__hip_bfloat16*)alloc(392L*384/2);
    __hip_bfloat16* attnb   = (__hip_bfloat16*)alloc(394L*384/2 + 64);
    __hip_bfloat16* hbufb   = (__hip_bfloat16*)alloc(394L*1536/2 + 64);
    __hip_bfloat16* qb      = (__hip_bfloat16*)alloc(12L*208*64/2);
    __hip_bfloat16* kb      = (__hip_bfloat16*)alloc(12L*208*64/2);
    __hip_bfloat16* vT      = (__hip_bfloat16*)alloc(12L*64*224/2);
    __hip_bfloat16* qkvwb   = (__hip_bfloat16*)alloc(12L*1152*384/2);
    __hip_bfloat16* projwb  = (__hip_bfloat16*)alloc(12L*384*384/2);
    __hip_bfloat16* fc1wb   = (__hip_bfloat16*)alloc(12L*1536*384/2);
    __hip_bfloat16* fc2wb   = (__hip_bfloat16*)alloc(12L*384*1536/2);
    __hip_bfloat16* apoutwb = (__hip_bfloat16*)alloc(384L*384/2);

    // ---- setup: one conversion kernel (weights + vT pad) ----
    {
        long tot4 = (5308416L + 1769472 + 2*7077888 + 147456) / 4;
        int blocks = (int)((tot4 + 255) / 256);
        cvt_all_k<<<blocks, 256, 0, stream>>>(
            qkv_w, proj_w, fc1_w, fc2_w, ap_out_w,
            qkvwb, projwb, fc1wb, fc2wb, apoutwb, vT);
    }

    // ---- tokenizer ----
    prep_w2_k<<<5, 256, 0, stream>>>(ap_in_w, ap_in_b, fp_w, fp_b,
                                     cls_tok, pos_emb, W2, b2, x);
    prep_head_k<<<4, 64, 0, stream>>>(W2, b2, hGm);
    tok_attn_k<<<dim3(196,4,2), 256, 0, stream>>>(img, hGm, W2, b2, pooledb);
    outproj_x_k<<<dim3(25,6), 64, 0, stream>>>(pooledb, apoutwb, ap_out_b, pos_emb, x);

    // ---- ViT trunk (5 dispatches per layer, column-parallel) ----
    for (int i = 0; i < 12; ++i) {
        ln_gemm_k<1><<<dim3(25,18), 64, 0, stream>>>(
            x, ln1_g + i*384, ln1_b + i*384, qkvwb + (long)i*1152*384,
            qkv_b + i*1152, qb, kb, vT, 394, 1152);
        attn_flash_k<<<dim3(13,12), 64, 0, stream>>>(qb, kb, vT, attnb);
        gemm_mfma_k<false,true,false><<<dim3(25,6,1), 64, 0, stream>>>(
            attnb, projwb + (long)i*384*384, proj_b + i*384, x, x,
            394, 384, 384, 384, 384, 384, 384, 0);
        ln_gemm_k<2><<<dim3(25,24), 64, 0, stream>>>(
            x, ln2_g + i*384, ln2_b + i*384, fc1wb + (long)i*1536*384,
            fc1_b + i*1536, hbufb, nullptr, nullptr, 394, 1536);
        gemm_mfma_k<false,true,false><<<dim3(25,6,1), 64, 0, stream>>>(
            hbufb, fc2wb + (long)i*384*1536, fc2_b + i*384, x, x,
            394, 384, 1536, 1536, 1536, 384, 1536, 0);
    }

    // ---- head ----
    head_k<<<10, 256, 0, stream>>>(x, norm_g, norm_b, head_w, head_b, out);
}